// Round 11
// baseline (697.835 us; speedup 1.0000x reference)
//
#include <hip/hip_runtime.h>
#include <hip/hip_bf16.h>
#include <math.h>

// Problem constants (from reference)
#define N_NODES 100000
#define F_IN    256
#define HID     128
#define NCLS    32
#define NEDGES  1600000
#define EPS_C   0.1f
#define GAMMA_C 0.1f

// CSR build: radix partition into 782 buckets of 128 nodes, no global atomics
#define NBK   782                  // ceil(100000/128)
#define CHUNK 4096
#define NCH   391                  // ceil(1600000/4096)
#define BMAX  4096                 // bucket cap for k_build LDS (mean 2046, +45 sigma)

typedef __attribute__((ext_vector_type(8))) short short8;   // 8 bf16 = 4 VGPRs (MFMA A/B frag)
typedef __attribute__((ext_vector_type(4))) float floatx4;  // MFMA C/D frag

__device__ __forceinline__ float bf2f(unsigned short u) {
    union { unsigned int u; float f; } c;
    c.u = ((unsigned int)u) << 16;
    return c.f;
}
__device__ __forceinline__ unsigned short f2bf(float f) {
    union { float f; unsigned int u; } c; c.f = f;
    unsigned int u = c.u;
    u += 0x7FFFu + ((u >> 16) & 1u);   // round-to-nearest-even
    return (unsigned short)(u >> 16);
}

__device__ __forceinline__ short8 cvt8(float4 u, float4 v) {
    short8 r;
    r[0] = (short)f2bf(u.x); r[1] = (short)f2bf(u.y);
    r[2] = (short)f2bf(u.z); r[3] = (short)f2bf(u.w);
    r[4] = (short)f2bf(v.x); r[5] = (short)f2bf(v.y);
    r[6] = (short)f2bf(v.z); r[7] = (short)f2bf(v.w);
    return r;
}

// Polymorphic scalar load: md=1 -> buffer is f32, md=0 -> bf16 (epilogue bias only)
__device__ __forceinline__ float ldf(const void* p, size_t i, int md) {
    return md ? ((const float*)p)[i] : bf2f(((const unsigned short*)p)[i]);
}

// ---------------------------------------------------------------- dtype probe
__global__ void k_detect(const unsigned short* __restrict__ x, int* __restrict__ mode) {
    __shared__ int cnt;
    if (threadIdx.x == 0) cnt = 0;
    __syncthreads();
    float v = fabsf(bf2f(x[2 * threadIdx.x]));
    if (v > 1e4f || !isfinite(v)) atomicAdd(&cnt, 1);
    __syncthreads();
    if (threadIdx.x == 0) *mode = (cnt >= 8) ? 1 : 0;
}

// ---------------------------------------------------------------- pre-convert
__global__ __launch_bounds__(256) void k_cvtx(const void* __restrict__ x,
                                              unsigned short* __restrict__ xbf,
                                              const int* __restrict__ dmode, int n8) {
    if (!dmode[0]) return;
    const float* xf = (const float*)x;
    int stride = gridDim.x * 256;
    for (int i = blockIdx.x * 256 + threadIdx.x; i < n8; i += stride) {
        const float* q = xf + (size_t)i * 8;
        float4 u = *(const float4*)q, v = *(const float4*)(q + 4);
        *(short8*)(xbf + (size_t)i * 8) = cvt8(u, v);
    }
}

// Weight matrices f32 -> bf16 into one contiguous buffer.
__global__ __launch_bounds__(256) void k_cvtw(const void* __restrict__ w1,
                                              const void* __restrict__ w2,
                                              const void* __restrict__ w3,
                                              const void* __restrict__ w4,
                                              unsigned short* __restrict__ out,
                                              const int* __restrict__ dmode) {
    if (!dmode[0]) return;
    int i = blockIdx.x * 256 + threadIdx.x;     // 8-elem group index
    const float* src; int off;
    if (i < 4096)      { src = (const float*)w1; off = i; }
    else if (i < 6144) { src = (const float*)w2; off = i - 4096; }
    else if (i < 6656) { src = (const float*)w3; off = i - 6144; }
    else if (i < 6784) { src = (const float*)w4; off = i - 6656; }
    else return;
    const float* q = src + (size_t)off * 8;
    *(short8*)(out + (size_t)i * 8) = cvt8(*(const float4*)q, *(const float4*)(q + 4));
}

// ---------------------------------------------------------------- CSR build v3
__global__ __launch_bounds__(256) void k_hist2(const int* __restrict__ ecol,
                                               int* __restrict__ hist, int e) {
    __shared__ int lh[NBK];
    for (int i = threadIdx.x; i < NBK; i += 256) lh[i] = 0;
    __syncthreads();
    int base = blockIdx.x * CHUNK;
    int lim = base + CHUNK; if (lim > e) lim = e;
    for (int i = base + threadIdx.x; i < lim; i += 256)
        atomicAdd(&lh[ecol[i] >> 7], 1);
    __syncthreads();
    for (int i = threadIdx.x; i < NBK; i += 256) hist[blockIdx.x * NBK + i] = lh[i];
}

__global__ __launch_bounds__(256) void k_tot(const int* __restrict__ hist, int* __restrict__ tot) {
    __shared__ int s[256];
    int b = blockIdx.x;
    int v = 0;
    for (int blk = threadIdx.x; blk < NCH; blk += 256) v += hist[blk * NBK + b];
    s[threadIdx.x] = v;
    __syncthreads();
#pragma unroll
    for (int off = 128; off > 0; off >>= 1) {
        if (threadIdx.x < off) s[threadIdx.x] += s[threadIdx.x + off];
        __syncthreads();
    }
    if (threadIdx.x == 0) tot[b] = s[0];
}

__global__ void k_bscan(const int* __restrict__ tot, int* __restrict__ bbase) {
    __shared__ int s[1024];
    int v = (threadIdx.x < NBK) ? tot[threadIdx.x] : 0;
    s[threadIdx.x] = v;
    __syncthreads();
#pragma unroll
    for (int off = 1; off < 1024; off <<= 1) {
        int t = (threadIdx.x >= off) ? s[threadIdx.x - off] : 0;
        __syncthreads();
        s[threadIdx.x] += t;
        __syncthreads();
    }
    if (threadIdx.x < NBK) bbase[threadIdx.x] = s[threadIdx.x] - v;
}

__global__ __launch_bounds__(512) void k_colscan(const int* __restrict__ hist,
                                                 const int* __restrict__ bbase,
                                                 int* __restrict__ off) {
    __shared__ int s[512];
    int b = blockIdx.x, t = threadIdx.x;
    int v = (t < NCH) ? hist[t * NBK + b] : 0;
    s[t] = v;
    __syncthreads();
#pragma unroll
    for (int o = 1; o < 512; o <<= 1) {
        int u = (t >= o) ? s[t - o] : 0;
        __syncthreads();
        s[t] += u;
        __syncthreads();
    }
    if (t < NCH) off[t * NBK + b] = s[t] - v + bbase[b];
}

// v4: sbk[] records each edge's bucket during the scatter -> the final
// placement loop does ONE LDS read instead of a 10-step binary search.
__global__ __launch_bounds__(256) void k_pass3(
    const int* __restrict__ erow, const int* __restrict__ ecol,
    const int* __restrict__ off, unsigned int* __restrict__ pairs, int e)
{
    __shared__ int lh[NBK];
    __shared__ int lex[NBK];
    __shared__ int cur[NBK];
    __shared__ int wsum[256];
    __shared__ unsigned int sp[CHUNK];
    __shared__ unsigned short sbk[CHUNK];
    int base = blockIdx.x * CHUNK;
    int lim = base + CHUNK; if (lim > e) lim = e;
    int cnt = lim - base;

    for (int i = threadIdx.x; i < NBK; i += 256) lh[i] = 0;
    __syncthreads();
    for (int i = base + threadIdx.x; i < lim; i += 256)
        atomicAdd(&lh[ecol[i] >> 7], 1);
    __syncthreads();

    int t4 = threadIdx.x * 4;
    int a0 = (t4 + 0 < NBK) ? lh[t4 + 0] : 0;
    int a1 = (t4 + 1 < NBK) ? lh[t4 + 1] : 0;
    int a2 = (t4 + 2 < NBK) ? lh[t4 + 2] : 0;
    int a3 = (t4 + 3 < NBK) ? lh[t4 + 3] : 0;
    int mysum = a0 + a1 + a2 + a3;
    wsum[threadIdx.x] = mysum;
    __syncthreads();
#pragma unroll
    for (int o = 1; o < 256; o <<= 1) {
        int u = (threadIdx.x >= o) ? wsum[threadIdx.x - o] : 0;
        __syncthreads();
        wsum[threadIdx.x] += u;
        __syncthreads();
    }
    int run = wsum[threadIdx.x] - mysum;
    if (t4 + 0 < NBK) { lex[t4 + 0] = run;            cur[t4 + 0] = run; }
    if (t4 + 1 < NBK) { lex[t4 + 1] = run + a0;       cur[t4 + 1] = run + a0; }
    if (t4 + 2 < NBK) { lex[t4 + 2] = run + a0 + a1;  cur[t4 + 2] = run + a0 + a1; }
    if (t4 + 3 < NBK) { lex[t4 + 3] = run + a0 + a1 + a2; cur[t4 + 3] = run + a0 + a1 + a2; }
    __syncthreads();

    for (int i = base + threadIdx.x; i < lim; i += 256) {
        int dst = ecol[i], src = erow[i];
        int b = dst >> 7;
        int p = atomicAdd(&cur[b], 1);
        sp[p] = ((unsigned int)src << 7) | (unsigned int)(dst & 127);
        sbk[p] = (unsigned short)b;
    }
    __syncthreads();

    for (int i = threadIdx.x; i < cnt; i += 256) {
        int b = sbk[i];
        pairs[off[blockIdx.x * NBK + b] + (i - lex[b])] = sp[i];
    }
}

__global__ __launch_bounds__(256) void k_build(
    const int* __restrict__ tot, const int* __restrict__ bbase,
    const unsigned int* __restrict__ pairs,
    int* __restrict__ srt, int* __restrict__ row_start, int* __restrict__ cend,
    float* __restrict__ dinv, int n)
{
    __shared__ int lh[128];
    __shared__ int lo[128];
    __shared__ unsigned int se[BMAX];
    int b = blockIdx.x;
    int nb = tot[b]; if (nb > BMAX) nb = BMAX;
    int base = bbase[b];
    if (threadIdx.x < 128) lh[threadIdx.x] = 0;
    __syncthreads();
    for (int e = threadIdx.x; e < nb; e += 256) {
        unsigned int pk = pairs[(size_t)base + e];
        se[e] = pk;
        atomicAdd(&lh[pk & 127u], 1);
    }
    __syncthreads();
    if (threadIdx.x < 128) lo[threadIdx.x] = lh[threadIdx.x];
    __syncthreads();
#pragma unroll
    for (int off = 1; off < 128; off <<= 1) {
        int t = (threadIdx.x < 128 && threadIdx.x >= off) ? lo[threadIdx.x - off] : 0;
        __syncthreads();
        if (threadIdx.x < 128) lo[threadIdx.x] += t;
        __syncthreads();
    }
    int node = b * 128 + threadIdx.x;
    if (threadIdx.x < 128 && node < n) {
        int inc = lo[threadIdx.x], cnt = lh[threadIdx.x];
        row_start[node] = base + inc - cnt;
        cend[node]      = base + inc;
        dinv[node]      = rsqrtf((float)cnt + 1.0f);
    }
    __syncthreads();
    if (threadIdx.x < 128) lh[threadIdx.x] = lo[threadIdx.x] - lh[threadIdx.x];
    __syncthreads();
    for (int e = threadIdx.x; e < nb; e += 256) {
        unsigned int pk = se[e];
        int pos = atomicAdd(&lh[pk & 127u], 1);
        srt[base + pos] = (int)(pk >> 7);
    }
}

// ---------------------------------------------------------------- degree sort
// Counting sort of nodes into 64 degree bins -> ord[] permutation. Gathers
// process nodes in degree order so each wave is degree-uniform (kills the
// max-of-k Poisson divergence waste).
__global__ void k_dzero(int* __restrict__ dh) { dh[threadIdx.x] = 0; }

__global__ __launch_bounds__(256) void k_dhist(const int* __restrict__ rs,
                                               const int* __restrict__ ce,
                                               int* __restrict__ dh, int n) {
    __shared__ int lh[64];
    if (threadIdx.x < 64) lh[threadIdx.x] = 0;
    __syncthreads();
    for (int i = blockIdx.x * 256 + threadIdx.x; i < n; i += gridDim.x * 256) {
        int d = ce[i] - rs[i]; if (d > 63) d = 63;
        atomicAdd(&lh[d], 1);
    }
    __syncthreads();
    if (threadIdx.x < 64 && lh[threadIdx.x]) atomicAdd(&dh[threadIdx.x], lh[threadIdx.x]);
}

__global__ void k_dscan(const int* __restrict__ dh, int* __restrict__ dcur) {
    __shared__ int s[64];
    int v = dh[threadIdx.x]; s[threadIdx.x] = v; __syncthreads();
#pragma unroll
    for (int o = 1; o < 64; o <<= 1) {
        int t = (threadIdx.x >= o) ? s[threadIdx.x - o] : 0;
        __syncthreads(); s[threadIdx.x] += t; __syncthreads();
    }
    dcur[threadIdx.x] = s[threadIdx.x] - v;   // exclusive base = start cursor
}

__global__ __launch_bounds__(256) void k_dscat(const int* __restrict__ rs,
                                               const int* __restrict__ ce,
                                               int* __restrict__ dcur,
                                               int* __restrict__ ord, int n) {
    for (int i = blockIdx.x * 256 + threadIdx.x; i < n; i += gridDim.x * 256) {
        int d = ce[i] - rs[i]; if (d > 63) d = 63;
        ord[atomicAdd(&dcur[d], 1)] = i;
    }
}

// ---------------------------------------------------------------- weights
__global__ void k_aw(const void* __restrict__ W, unsigned short* __restrict__ aw,
                     const int* __restrict__ dmode, int d) {
    int idx = blockIdx.x * blockDim.x + threadIdx.x;
    if (idx >= d * d) return;
    int md = dmode[0];
    int n = idx / d, k = idx - n * d;
    float v = ldf(W, n * d + k, md) - ldf(W, k * d + n, md) - ((n == k) ? GAMMA_C : 0.0f);
    aw[idx] = f2bf(v);
}

// ---------------------------------------------------------------- GEMM v8
// (unchanged from R10 -- single-barrier pure-bf16, proven)
template<int K, int NCB, int NCF, int EPI, int NSPLIT, bool ASEL, bool BSEL>
__global__ __launch_bounds__(512) void k_gemm6(
    const void* A, const unsigned short* Acvt,
    const void* B, const unsigned short* Bcvt, const void* bias,
    unsigned short* Cout,
    const unsigned short* agg, const unsigned short* xw, const float* dinv,
    const int* dmode, void* opout, int M)
{
    constexpr int KP = K + 8;
    constexpr int NT = NCB / 16;
    constexpr int KS = K / 32;
    constexpr int SN = (NCB * K) / 4096;
    __shared__ __align__(16) unsigned short sB[NCB * KP];
    const int md = dmode[0];

    const unsigned short* Ab = (ASEL && md) ? Acvt : (const unsigned short*)A;
    const unsigned short* Bb = (BSEL && md) ? Bcvt : (const unsigned short*)B;

    const int rowblk = (NSPLIT > 1) ? ((int)blockIdx.x / NSPLIT) : (int)blockIdx.x;
    const int col0   = (NSPLIT > 1) ? ((int)blockIdx.x % NSPLIT) * NCB : 0;

    const int lane = threadIdx.x & 63;
    const int wave = threadIdx.x >> 6;
    const int l15  = lane & 15;
    const int quad = lane >> 4;
    const int row0 = rowblk * 128 + wave * 16;

    int ar = row0 + l15;
    int am = ar < M ? ar : M - 1;

    short8 a[KS];
#pragma unroll
    for (int s = 0; s < KS; ++s)
        a[s] = *(const short8*)(Ab + (size_t)am * K + s * 32 + quad * 8);

    if constexpr (SN >= 1) {
        short8 st[SN];
#pragma unroll
        for (int i = 0; i < SN; ++i) {
            int base = threadIdx.x * 8 + i * 4096;
            int r = base / K, c = base % K;
            st[i] = *(const short8*)(Bb + (size_t)(col0 + r) * K + c);
        }
#pragma unroll
        for (int i = 0; i < SN; ++i) {
            int base = threadIdx.x * 8 + i * 4096;
            int r = base / K, c = base % K;
            *(short8*)(sB + r * KP + c) = st[i];
        }
    } else {
        if (threadIdx.x < (NCB * K) / 8) {
            int base = threadIdx.x * 8;
            int r = base / K, c = base % K;
            *(short8*)(sB + r * KP + c) =
                *(const short8*)(Bb + (size_t)(col0 + r) * K + c);
        }
    }
    __builtin_amdgcn_sched_barrier(0);
    __syncthreads();

    floatx4 acc[NT];
#pragma unroll
    for (int t = 0; t < NT; ++t) acc[t] = (floatx4){0.f, 0.f, 0.f, 0.f};

#pragma unroll
    for (int s = 0; s < KS; ++s) {
        short8 b[NT];
#pragma unroll
        for (int t = 0; t < NT; ++t)
            b[t] = *(const short8*)(sB + (t * 16 + l15) * KP + s * 32 + quad * 8);
#pragma unroll
        for (int t = 0; t < NT; ++t)
            acc[t] = __builtin_amdgcn_mfma_f32_16x16x32_bf16(a[s], b[t], acc[t], 0, 0, 0);
    }

    const unsigned short* Ares = Ab;
#pragma unroll
    for (int reg = 0; reg < 4; ++reg) {
        int rr = row0 + quad * 4 + reg;
        if (EPI == 4) {
            int rrc = rr < M ? rr : M - 1;
            float dv = dinv[rrc];
            float val[NT];
#pragma unroll
            for (int t = 0; t < NT; ++t) {
                int col = t * 16 + l15;
                float z = acc[t][reg]
                        + bf2f(agg[(size_t)rrc * NCF + col])
                        + dv * bf2f(xw[(size_t)rrc * NCF + col])
                        + ldf(bias, col, md);
                val[t] = bf2f(Ares[(size_t)rrc * K + col]) + EPS_C * tanhf(z);
            }
            float m = val[0];
#pragma unroll
            for (int t = 1; t < NT; ++t) m = fmaxf(m, val[t]);
#pragma unroll
            for (int msk = 1; msk < 16; msk <<= 1) m = fmaxf(m, __shfl_xor(m, msk));
            float s = 0.f;
#pragma unroll
            for (int t = 0; t < NT; ++t) s += expf(val[t] - m);
#pragma unroll
            for (int msk = 1; msk < 16; msk <<= 1) s += __shfl_xor(s, msk);
            float ls = m + logf(s);
            if (rr < M) {
#pragma unroll
                for (int t = 0; t < NT; ++t) {
                    int col = t * 16 + l15;
                    float r = val[t] - ls;
                    if (md) ((float*)opout)[(size_t)rr * NCF + col] = r;
                    else    ((unsigned short*)opout)[(size_t)rr * NCF + col] = f2bf(r);
                }
            }
        } else {
            if (rr >= M) continue;
#pragma unroll
            for (int t = 0; t < NT; ++t) {
                int gcol = col0 + t * 16 + l15;
                float v = acc[t][reg];
                if (EPI == 0) { v += ldf(bias, gcol, md); v = v > 0.f ? v : 0.f; }
                else if (EPI == 5) { v *= dinv[rr]; }
                else if (EPI == 3) {
                    float dv = dinv[rr];
                    float z = v + bf2f(agg[(size_t)rr * NCF + gcol])
                            + dv * bf2f(xw[(size_t)rr * NCF + gcol])
                            + ldf(bias, gcol, md);
                    v = bf2f(Ares[(size_t)rr * K + gcol]) + EPS_C * tanhf(z);
                }
                Cout[(size_t)rr * NCF + gcol] = f2bf(v);
            }
        }
    }
}

// ---------------------------------------------------------------- fused lin2+phi2
__global__ __launch_bounds__(256) void k_lin2phi2(
    const unsigned short* __restrict__ A,
    const void* __restrict__ B1, const unsigned short* __restrict__ B1c,
    const void* __restrict__ bias,
    const void* __restrict__ B2, const unsigned short* __restrict__ B2c,
    unsigned short* __restrict__ h3, unsigned short* __restrict__ xws2,
    const float* __restrict__ dinv, const int* __restrict__ dmode, int M)
{
    constexpr int K1 = 128, KP1 = 136, KP2 = 40;
    __shared__ __align__(16) unsigned short sB1[32 * KP1];
    __shared__ __align__(16) unsigned short sB2[32 * KP2];
    __shared__ __align__(16) unsigned short sT[128 * KP2];
    const int md = dmode[0];

    const unsigned short* B1b = md ? B1c : (const unsigned short*)B1;
    const unsigned short* B2b = md ? B2c : (const unsigned short*)B2;

    const int lane = threadIdx.x & 63;
    const int wave = threadIdx.x >> 6;
    const int l15  = lane & 15;
    const int quad = lane >> 4;
    const int row0 = blockIdx.x * 128 + wave * 32;

    int am[2];
#pragma unroll
    for (int rt = 0; rt < 2; ++rt) {
        int r = row0 + rt * 16 + l15;
        am[rt] = r < M ? r : M - 1;
    }

    short8 a1[4][2];
#pragma unroll
    for (int s = 0; s < 4; ++s)
#pragma unroll
        for (int rt = 0; rt < 2; ++rt)
            a1[s][rt] = *(const short8*)(A + (size_t)am[rt] * K1 + s * 32 + quad * 8);

    short8 s1[2], s2;
    const bool has2 = threadIdx.x * 8 < 1024;
#pragma unroll
    for (int i = 0; i < 2; ++i)
        s1[i] = *(const short8*)(B1b + threadIdx.x * 8 + i * 2048);
    if (has2)
        s2 = *(const short8*)(B2b + threadIdx.x * 8);
#pragma unroll
    for (int i = 0; i < 2; ++i) {
        int base = threadIdx.x * 8 + i * 2048;
        int r = base / K1, c = base - r * K1;
        *(short8*)(sB1 + r * KP1 + c) = s1[i];
    }
    if (has2) {
        int base = threadIdx.x * 8;
        int r = base / 32, c = base - r * 32;
        *(short8*)(sB2 + r * KP2 + c) = s2;
    }
    __builtin_amdgcn_sched_barrier(0);
    __syncthreads();

    floatx4 acc[2][2];
#pragma unroll
    for (int rt = 0; rt < 2; ++rt) { acc[rt][0] = (floatx4){0,0,0,0}; acc[rt][1] = (floatx4){0,0,0,0}; }

#pragma unroll
    for (int s = 0; s < 4; ++s) {
#pragma unroll
        for (int rt = 0; rt < 2; ++rt) {
#pragma unroll
            for (int t = 0; t < 2; ++t) {
                short8 b = *(const short8*)(sB1 + (t * 16 + l15) * KP1 + s * 32 + quad * 8);
                acc[rt][t] = __builtin_amdgcn_mfma_f32_16x16x32_bf16(a1[s][rt], b, acc[rt][t], 0, 0, 0);
            }
        }
    }
#pragma unroll
    for (int rt = 0; rt < 2; ++rt)
#pragma unroll
        for (int reg = 0; reg < 4; ++reg) {
            int rr = row0 + rt * 16 + quad * 4 + reg;
            int lr = wave * 32 + rt * 16 + quad * 4 + reg;
#pragma unroll
            for (int t = 0; t < 2; ++t) {
                int col = t * 16 + l15;
                unsigned short hv = f2bf(acc[rt][t][reg] + ldf(bias, col, md));
                sT[lr * KP2 + col] = hv;
                if (rr < M) h3[(size_t)rr * 32 + col] = hv;
            }
        }
    __syncthreads();

    floatx4 a2[2][2];
#pragma unroll
    for (int rt = 0; rt < 2; ++rt) {
        short8 a = *(const short8*)(sT + (wave * 32 + rt * 16 + l15) * KP2 + quad * 8);
#pragma unroll
        for (int t = 0; t < 2; ++t) {
            short8 b = *(const short8*)(sB2 + (t * 16 + l15) * KP2 + quad * 8);
            a2[rt][t] = __builtin_amdgcn_mfma_f32_16x16x32_bf16(a, b, (floatx4){0,0,0,0}, 0, 0, 0);
        }
    }
#pragma unroll
    for (int rt = 0; rt < 2; ++rt)
#pragma unroll
        for (int reg = 0; reg < 4; ++reg) {
            int rr = row0 + rt * 16 + quad * 4 + reg;
            if (rr >= M) continue;
            float dv = dinv[rr];
#pragma unroll
            for (int t = 0; t < 2; ++t)
                xws2[(size_t)rr * 32 + t * 16 + l15] = f2bf(dv * a2[rt][t][reg]);
        }
}

// ---------------------------------------------------------------- gather v6
// Row-major + degree-ordered nodes (ord[]): waves are degree-uniform, so
// wide lanes carry no divergence cost. gather128: 16 lanes/node x 16B
// (1 load per edge-row per lane -- half of v5's count), 4 nodes/wave.
__global__ __launch_bounds__(256) void k_gather128(
    const int* __restrict__ srt, const int* __restrict__ rs,
    const int* __restrict__ cend, const int* __restrict__ ord,
    const unsigned short* __restrict__ xws, const float* __restrict__ dinv,
    unsigned short* __restrict__ agg, int n)
{
    int gid = blockIdx.x * 16 + (threadIdx.x >> 4);
    int l = threadIdx.x & 15;
    if (gid >= n) return;
    int node = ord[gid];
    int j = rs[node], end = cend[node];
    float ac[8] = {0.f, 0.f, 0.f, 0.f, 0.f, 0.f, 0.f, 0.f};
    int jend = j + ((end - j) & ~7);
    while (j < jend) {
        int idx[8];
#pragma unroll
        for (int k = 0; k < 8; ++k) idx[k] = srt[j + k];
        short8 p[8];
#pragma unroll
        for (int k = 0; k < 8; ++k)
            p[k] = *(const short8*)(xws + (size_t)idx[k] * 128 + l * 8);
#pragma unroll
        for (int k = 0; k < 8; ++k)
#pragma unroll
            for (int e = 0; e < 8; ++e)
                ac[e] += bf2f((unsigned short)p[k][e]);
        j += 8;
    }
    if (j < end) {
        int idx[8];
#pragma unroll
        for (int k = 0; k < 8; ++k) {
            int jj = j + k;
            idx[k] = srt[jj < end ? jj : end - 1];
        }
        short8 p[8];
#pragma unroll
        for (int k = 0; k < 8; ++k)
            p[k] = *(const short8*)(xws + (size_t)idx[k] * 128 + l * 8);
#pragma unroll
        for (int k = 0; k < 8; ++k) {
            if (j + k < end) {
#pragma unroll
                for (int e = 0; e < 8; ++e)
                    ac[e] += bf2f((unsigned short)p[k][e]);
            }
        }
    }
    float dn = dinv[node];
    short8 out;
#pragma unroll
    for (int e = 0; e < 8; ++e) out[e] = (short)f2bf(dn * ac[e]);
    *(short8*)(agg + (size_t)node * 128 + l * 8) = out;
}

// gather32 v3: 4 lanes/node x 16B, 16 nodes/wave (degree-uniform via ord).
__global__ __launch_bounds__(256) void k_gather32(
    const int* __restrict__ srt, const int* __restrict__ rs,
    const int* __restrict__ cend, const int* __restrict__ ord,
    const unsigned short* __restrict__ xws, const float* __restrict__ dinv,
    unsigned short* __restrict__ agg, int n)
{
    int gid = blockIdx.x * 64 + (threadIdx.x >> 2);
    int l = threadIdx.x & 3;
    if (gid >= n) return;
    int node = ord[gid];
    int j = rs[node], end = cend[node];
    float ac[8] = {0.f, 0.f, 0.f, 0.f, 0.f, 0.f, 0.f, 0.f};
    int jend = j + ((end - j) & ~7);
    while (j < jend) {
        int idx[8];
#pragma unroll
        for (int k = 0; k < 8; ++k) idx[k] = srt[j + k];
        short8 p[8];
#pragma unroll
        for (int k = 0; k < 8; ++k)
            p[k] = *(const short8*)(xws + (size_t)idx[k] * 32 + l * 8);
#pragma unroll
        for (int k = 0; k < 8; ++k)
#pragma unroll
            for (int e = 0; e < 8; ++e)
                ac[e] += bf2f((unsigned short)p[k][e]);
        j += 8;
    }
    if (j < end) {
        int idx[8];
#pragma unroll
        for (int k = 0; k < 8; ++k) {
            int jj = j + k;
            idx[k] = srt[jj < end ? jj : end - 1];
        }
        short8 p[8];
#pragma unroll
        for (int k = 0; k < 8; ++k)
            p[k] = *(const short8*)(xws + (size_t)idx[k] * 32 + l * 8);
#pragma unroll
        for (int k = 0; k < 8; ++k) {
            if (j + k < end) {
#pragma unroll
                for (int e = 0; e < 8; ++e)
                    ac[e] += bf2f((unsigned short)p[k][e]);
            }
        }
    }
    float dn = dinv[node];
    short8 out;
#pragma unroll
    for (int e = 0; e < 8; ++e) out[e] = (short)f2bf(dn * ac[e]);
    *(short8*)(agg + (size_t)node * 32 + l * 8) = out;
}

// ---------------------------------------------------------------- launch
extern "C" void kernel_launch(void* const* d_in, const int* in_sizes, int n_in,
                              void* d_out, int out_size, void* d_ws, size_t ws_size,
                              hipStream_t stream)
{
    const void* x      = d_in[0];
    const void* lin1_w = d_in[1];
    const void* lin1_b = d_in[2];
    const void* lin2_w = d_in[3];
    const void* lin2_b = d_in[4];
    const void* W1     = d_in[5];
    const void* phi1w  = d_in[6];
    const void* b1     = d_in[7];
    const void* W2     = d_in[8];
    const void* phi2w  = d_in[9];
    const void* b2     = d_in[10];
    const int* eidx    = (const int*)d_in[11];
    const int* erow = eidx;
    const int* ecol = eidx + NEDGES;

    // Workspace (high-water ~87.7 MB; ord/dh appended after agg1 span)
    char* ws = (char*)d_ws;
    float* dinv          = (float*)ws;                    // [N] f32
    int*   dmode         = (int*)(ws + 400000);
    unsigned short* aw1  = (unsigned short*)(ws + 401408);
    unsigned short* aw2  = (unsigned short*)(ws + 435200);
    int* tot             = (int*)(ws + 440320);           // [782]
    int* bbase           = (int*)(ws + 443648);           // [782]
    int* row_start       = (int*)(ws + 446976);           // [N]
    int* cend            = (int*)(ws + 846976);           // [N]
    int* srt             = (int*)(ws + 1246976);          // [E] 6.4MB
    int* hist            = (int*)(ws + 7646976);          // [NCH*NBK]
    int* offb            = (int*)(ws + 8870912);          // [NCH*NBK] ends 10093960
    unsigned short* wbf  = (unsigned short*)(ws + 10094080); // 108.5KB, in the gap
    unsigned short* h1   = (unsigned short*)(ws + 10485760);          // [N,128]
    unsigned short* xws1 = h1 + (size_t)N_NODES * HID;                // [N,128]
    unsigned short* agg1 = xws1 + (size_t)N_NODES * HID;              // [N,128]
    unsigned short* h2   = xws1;   // EPI3 in-place (read-before-write per thread)
    unsigned short* h3   = h1;     // h1 dead after EPI3
    unsigned short* xws2 = agg1;   // agg1 dead after EPI3
    unsigned short* agg2 = agg1 + (size_t)N_NODES * NCLS;
    unsigned int* pairs  = (unsigned int*)agg1;  // consumed by k_build before cvtx
    unsigned short* xbf  = xws1;   // [N,256] bf16 = xws1+agg1 span; dead after lin1
    int* ord             = (int*)(ws + 87285760);         // [N] after agg1 span
    int* dh              = (int*)(ws + 87685760);         // [64]
    int* dcur            = dh + 64;                       // [64]

    // converted-weight segments (elems): lin1_w 32768 | phi1w 16384 | lin2_w 4096 | phi2w 1024
    unsigned short* bw1 = wbf;
    unsigned short* bp1 = wbf + 32768;
    unsigned short* bw2 = wbf + 49152;
    unsigned short* bp2 = wbf + 53248;

    const int GB = 256;
    const int NB5 = (N_NODES + 127) / 128;     // 782 blocks (128 rows/block, 8 waves)
    k_detect<<<1, 256, 0, stream>>>((const unsigned short*)x, dmode);

    // CSR build v3: radix partition, zero global atomics
    k_hist2<<<NCH, 256, 0, stream>>>(ecol, hist, NEDGES);
    k_tot<<<NBK, 256, 0, stream>>>(hist, tot);
    k_bscan<<<1, 1024, 0, stream>>>(tot, bbase);
    k_colscan<<<NBK, 512, 0, stream>>>(hist, bbase, offb);
    k_pass3<<<NCH, 256, 0, stream>>>(erow, ecol, offb, pairs, NEDGES);
    k_build<<<NBK, 256, 0, stream>>>(tot, bbase, pairs, srt, row_start, cend, dinv, N_NODES);

    // degree-sorted node order for the gathers
    k_dzero<<<1, 64, 0, stream>>>(dh);
    k_dhist<<<98, 256, 0, stream>>>(row_start, cend, dh, N_NODES);
    k_dscan<<<1, 64, 0, stream>>>(dh, dcur);
    k_dscat<<<98, 256, 0, stream>>>(row_start, cend, dcur, ord, N_NODES);

    // antisymmetric weights + bf16 pre-conversion
    k_aw<<<(HID * HID + GB - 1) / GB, GB, 0, stream>>>(W1, aw1, dmode, HID);
    k_aw<<<(NCLS * NCLS + GB - 1) / GB, GB, 0, stream>>>(W2, aw2, dmode, NCLS);
    k_cvtw<<<27, 256, 0, stream>>>(lin1_w, phi1w, lin2_w, phi2w, wbf, dmode);
    k_cvtx<<<2048, 256, 0, stream>>>(x, xbf, dmode, N_NODES * F_IN / 8);

    // h1 = relu(x @ lin1_w.T + lin1_b)   col-split x2 (33.8KB LDS), bf16 path
    k_gemm6<256, 64, 128, 0, 2, true, true><<<NB5 * 2, 512, 0, stream>>>(
        x, xbf, lin1_w, bw1, lin1_b, h1, nullptr, nullptr, nullptr, dmode, nullptr, N_NODES);
    // xws1 = dinv * (h1 @ phi1_w.T)      full B in LDS (34.8KB), one barrier
    k_gemm6<128, 128, 128, 5, 1, false, true><<<NB5, 512, 0, stream>>>(
        h1, nullptr, phi1w, bp1, nullptr, xws1, nullptr, nullptr, dinv, dmode, nullptr, N_NODES);
    // agg1 = dinv * gather(xws1)         degree-ordered
    k_gather128<<<(N_NODES + 15) / 16, 256, 0, stream>>>(
        srt, row_start, cend, ord, xws1, dinv, agg1, N_NODES);
    // h2 = h1 + EPS*tanh(h1@aw1.T + agg1 + dinv*xws1 + b1)   (in-place on xws1)
    k_gemm6<128, 128, 128, 3, 1, false, false><<<NB5, 512, 0, stream>>>(
        h1, nullptr, aw1, nullptr, b1, h2, agg1, xws1, dinv, dmode, nullptr, N_NODES);
    // h3 = h2@lin2_w.T + lin2_b ; xws2 = dinv*(h3@phi2_w.T)   (fused)
    k_lin2phi2<<<(N_NODES + 127) / 128, 256, 0, stream>>>(
        h2, lin2_w, bw2, lin2_b, phi2w, bp2, h3, xws2, dinv, dmode, N_NODES);
    // agg2 = dinv * gather(xws2)         degree-ordered
    k_gather32<<<(N_NODES + 63) / 64, 256, 0, stream>>>(
        srt, row_start, cend, ord, xws2, dinv, agg2, N_NODES);
    // out = log_softmax(h3 + EPS*tanh(h3@aw2.T + agg2 + dinv*xws2 + b2))  (fused)
    k_gemm6<32, 32, 32, 4, 1, false, false><<<NB5, 512, 0, stream>>>(
        h3, nullptr, aw2, nullptr, b2, nullptr, agg2, xws2, dinv, dmode, d_out, N_NODES);
}

// Round 12
// 434.610 us; speedup vs baseline: 1.6057x; 1.6057x over previous
//
#include <hip/hip_runtime.h>
#include <hip/hip_bf16.h>
#include <math.h>

// Problem constants (from reference)
#define N_NODES 100000
#define F_IN    256
#define HID     128
#define NCLS    32
#define NEDGES  1600000
#define EPS_C   0.1f
#define GAMMA_C 0.1f

// CSR build: radix partition into 782 buckets of 128 nodes, no global atomics
#define NBK   782                  // ceil(100000/128)
#define CHUNK 4096
#define NCH   391                  // ceil(1600000/4096)
#define BMAX  4096                 // bucket cap for k_build LDS (mean 2046, +45 sigma)

typedef __attribute__((ext_vector_type(8))) short short8;   // 8 bf16 = 4 VGPRs (MFMA A/B frag)
typedef __attribute__((ext_vector_type(4))) float floatx4;  // MFMA C/D frag

__device__ __forceinline__ float bf2f(unsigned short u) {
    union { unsigned int u; float f; } c;
    c.u = ((unsigned int)u) << 16;
    return c.f;
}
__device__ __forceinline__ unsigned short f2bf(float f) {
    union { float f; unsigned int u; } c; c.f = f;
    unsigned int u = c.u;
    u += 0x7FFFu + ((u >> 16) & 1u);   // round-to-nearest-even
    return (unsigned short)(u >> 16);
}

__device__ __forceinline__ short8 cvt8(float4 u, float4 v) {
    short8 r;
    r[0] = (short)f2bf(u.x); r[1] = (short)f2bf(u.y);
    r[2] = (short)f2bf(u.z); r[3] = (short)f2bf(u.w);
    r[4] = (short)f2bf(v.x); r[5] = (short)f2bf(v.y);
    r[6] = (short)f2bf(v.z); r[7] = (short)f2bf(v.w);
    return r;
}

// Polymorphic scalar load: md=1 -> buffer is f32, md=0 -> bf16 (epilogue bias only)
__device__ __forceinline__ float ldf(const void* p, size_t i, int md) {
    return md ? ((const float*)p)[i] : bf2f(((const unsigned short*)p)[i]);
}

// ---------------------------------------------------------------- dtype probe
__global__ void k_detect(const unsigned short* __restrict__ x, int* __restrict__ mode) {
    __shared__ int cnt;
    if (threadIdx.x == 0) cnt = 0;
    __syncthreads();
    float v = fabsf(bf2f(x[2 * threadIdx.x]));
    if (v > 1e4f || !isfinite(v)) atomicAdd(&cnt, 1);
    __syncthreads();
    if (threadIdx.x == 0) *mode = (cnt >= 8) ? 1 : 0;
}

// ---------------------------------------------------------------- pre-convert
__global__ __launch_bounds__(256) void k_cvtx(const void* __restrict__ x,
                                              unsigned short* __restrict__ xbf,
                                              const int* __restrict__ dmode, int n8) {
    if (!dmode[0]) return;
    const float* xf = (const float*)x;
    int stride = gridDim.x * 256;
    for (int i = blockIdx.x * 256 + threadIdx.x; i < n8; i += stride) {
        const float* q = xf + (size_t)i * 8;
        float4 u = *(const float4*)q, v = *(const float4*)(q + 4);
        *(short8*)(xbf + (size_t)i * 8) = cvt8(u, v);
    }
}

// Weight matrices f32 -> bf16 into one contiguous buffer.
__global__ __launch_bounds__(256) void k_cvtw(const void* __restrict__ w1,
                                              const void* __restrict__ w2,
                                              const void* __restrict__ w3,
                                              const void* __restrict__ w4,
                                              unsigned short* __restrict__ out,
                                              const int* __restrict__ dmode) {
    if (!dmode[0]) return;
    int i = blockIdx.x * 256 + threadIdx.x;     // 8-elem group index
    const float* src; int off;
    if (i < 4096)      { src = (const float*)w1; off = i; }
    else if (i < 6144) { src = (const float*)w2; off = i - 4096; }
    else if (i < 6656) { src = (const float*)w3; off = i - 6144; }
    else if (i < 6784) { src = (const float*)w4; off = i - 6656; }
    else return;
    const float* q = src + (size_t)off * 8;
    *(short8*)(out + (size_t)i * 8) = cvt8(*(const float4*)q, *(const float4*)(q + 4));
}

// ---------------------------------------------------------------- CSR build v3
__global__ __launch_bounds__(256) void k_hist2(const int* __restrict__ ecol,
                                               int* __restrict__ hist, int e) {
    __shared__ int lh[NBK];
    for (int i = threadIdx.x; i < NBK; i += 256) lh[i] = 0;
    __syncthreads();
    int base = blockIdx.x * CHUNK;
    int lim = base + CHUNK; if (lim > e) lim = e;
    for (int i = base + threadIdx.x; i < lim; i += 256)
        atomicAdd(&lh[ecol[i] >> 7], 1);
    __syncthreads();
    for (int i = threadIdx.x; i < NBK; i += 256) hist[blockIdx.x * NBK + i] = lh[i];
}

__global__ __launch_bounds__(256) void k_tot(const int* __restrict__ hist, int* __restrict__ tot) {
    __shared__ int s[256];
    int b = blockIdx.x;
    int v = 0;
    for (int blk = threadIdx.x; blk < NCH; blk += 256) v += hist[blk * NBK + b];
    s[threadIdx.x] = v;
    __syncthreads();
#pragma unroll
    for (int off = 128; off > 0; off >>= 1) {
        if (threadIdx.x < off) s[threadIdx.x] += s[threadIdx.x + off];
        __syncthreads();
    }
    if (threadIdx.x == 0) tot[b] = s[0];
}

__global__ void k_bscan(const int* __restrict__ tot, int* __restrict__ bbase) {
    __shared__ int s[1024];
    int v = (threadIdx.x < NBK) ? tot[threadIdx.x] : 0;
    s[threadIdx.x] = v;
    __syncthreads();
#pragma unroll
    for (int off = 1; off < 1024; off <<= 1) {
        int t = (threadIdx.x >= off) ? s[threadIdx.x - off] : 0;
        __syncthreads();
        s[threadIdx.x] += t;
        __syncthreads();
    }
    if (threadIdx.x < NBK) bbase[threadIdx.x] = s[threadIdx.x] - v;
}

__global__ __launch_bounds__(512) void k_colscan(const int* __restrict__ hist,
                                                 const int* __restrict__ bbase,
                                                 int* __restrict__ off) {
    __shared__ int s[512];
    int b = blockIdx.x, t = threadIdx.x;
    int v = (t < NCH) ? hist[t * NBK + b] : 0;
    s[t] = v;
    __syncthreads();
#pragma unroll
    for (int o = 1; o < 512; o <<= 1) {
        int u = (t >= o) ? s[t - o] : 0;
        __syncthreads();
        s[t] += u;
        __syncthreads();
    }
    if (t < NCH) off[t * NBK + b] = s[t] - v + bbase[b];
}

// sbk[] records each edge's bucket during the scatter -> the final
// placement loop does ONE LDS read instead of a 10-step binary search.
__global__ __launch_bounds__(256) void k_pass3(
    const int* __restrict__ erow, const int* __restrict__ ecol,
    const int* __restrict__ off, unsigned int* __restrict__ pairs, int e)
{
    __shared__ int lh[NBK];
    __shared__ int lex[NBK];
    __shared__ int cur[NBK];
    __shared__ int wsum[256];
    __shared__ unsigned int sp[CHUNK];
    __shared__ unsigned short sbk[CHUNK];
    int base = blockIdx.x * CHUNK;
    int lim = base + CHUNK; if (lim > e) lim = e;
    int cnt = lim - base;

    for (int i = threadIdx.x; i < NBK; i += 256) lh[i] = 0;
    __syncthreads();
    for (int i = base + threadIdx.x; i < lim; i += 256)
        atomicAdd(&lh[ecol[i] >> 7], 1);
    __syncthreads();

    int t4 = threadIdx.x * 4;
    int a0 = (t4 + 0 < NBK) ? lh[t4 + 0] : 0;
    int a1 = (t4 + 1 < NBK) ? lh[t4 + 1] : 0;
    int a2 = (t4 + 2 < NBK) ? lh[t4 + 2] : 0;
    int a3 = (t4 + 3 < NBK) ? lh[t4 + 3] : 0;
    int mysum = a0 + a1 + a2 + a3;
    wsum[threadIdx.x] = mysum;
    __syncthreads();
#pragma unroll
    for (int o = 1; o < 256; o <<= 1) {
        int u = (threadIdx.x >= o) ? wsum[threadIdx.x - o] : 0;
        __syncthreads();
        wsum[threadIdx.x] += u;
        __syncthreads();
    }
    int run = wsum[threadIdx.x] - mysum;
    if (t4 + 0 < NBK) { lex[t4 + 0] = run;            cur[t4 + 0] = run; }
    if (t4 + 1 < NBK) { lex[t4 + 1] = run + a0;       cur[t4 + 1] = run + a0; }
    if (t4 + 2 < NBK) { lex[t4 + 2] = run + a0 + a1;  cur[t4 + 2] = run + a0 + a1; }
    if (t4 + 3 < NBK) { lex[t4 + 3] = run + a0 + a1 + a2; cur[t4 + 3] = run + a0 + a1 + a2; }
    __syncthreads();

    for (int i = base + threadIdx.x; i < lim; i += 256) {
        int dst = ecol[i], src = erow[i];
        int b = dst >> 7;
        int p = atomicAdd(&cur[b], 1);
        sp[p] = ((unsigned int)src << 7) | (unsigned int)(dst & 127);
        sbk[p] = (unsigned short)b;
    }
    __syncthreads();

    for (int i = threadIdx.x; i < cnt; i += 256) {
        int b = sbk[i];
        pairs[off[blockIdx.x * NBK + b] + (i - lex[b])] = sp[i];
    }
}

__global__ __launch_bounds__(256) void k_build(
    const int* __restrict__ tot, const int* __restrict__ bbase,
    const unsigned int* __restrict__ pairs,
    int* __restrict__ srt, int* __restrict__ row_start, int* __restrict__ cend,
    float* __restrict__ dinv, int n)
{
    __shared__ int lh[128];
    __shared__ int lo[128];
    __shared__ unsigned int se[BMAX];
    int b = blockIdx.x;
    int nb = tot[b]; if (nb > BMAX) nb = BMAX;
    int base = bbase[b];
    if (threadIdx.x < 128) lh[threadIdx.x] = 0;
    __syncthreads();
    for (int e = threadIdx.x; e < nb; e += 256) {
        unsigned int pk = pairs[(size_t)base + e];
        se[e] = pk;
        atomicAdd(&lh[pk & 127u], 1);
    }
    __syncthreads();
    if (threadIdx.x < 128) lo[threadIdx.x] = lh[threadIdx.x];
    __syncthreads();
#pragma unroll
    for (int off = 1; off < 128; off <<= 1) {
        int t = (threadIdx.x < 128 && threadIdx.x >= off) ? lo[threadIdx.x - off] : 0;
        __syncthreads();
        if (threadIdx.x < 128) lo[threadIdx.x] += t;
        __syncthreads();
    }
    int node = b * 128 + threadIdx.x;
    if (threadIdx.x < 128 && node < n) {
        int inc = lo[threadIdx.x], cnt = lh[threadIdx.x];
        row_start[node] = base + inc - cnt;
        cend[node]      = base + inc;
        dinv[node]      = rsqrtf((float)cnt + 1.0f);
    }
    __syncthreads();
    if (threadIdx.x < 128) lh[threadIdx.x] = lo[threadIdx.x] - lh[threadIdx.x];
    __syncthreads();
    for (int e = threadIdx.x; e < nb; e += 256) {
        unsigned int pk = se[e];
        int pos = atomicAdd(&lh[pk & 127u], 1);
        srt[base + pos] = (int)(pk >> 7);
    }
}

// ---------------------------------------------------------------- degree sort
// Counting sort of nodes into 64 degree bins -> ord[] permutation.
__global__ void k_dzero(int* __restrict__ dh) { dh[threadIdx.x] = 0; }

__global__ __launch_bounds__(256) void k_dhist(const int* __restrict__ rs,
                                               const int* __restrict__ ce,
                                               int* __restrict__ dh, int n) {
    __shared__ int lh[64];
    if (threadIdx.x < 64) lh[threadIdx.x] = 0;
    __syncthreads();
    for (int i = blockIdx.x * 256 + threadIdx.x; i < n; i += gridDim.x * 256) {
        int d = ce[i] - rs[i]; if (d > 63) d = 63;
        atomicAdd(&lh[d], 1);
    }
    __syncthreads();
    if (threadIdx.x < 64 && lh[threadIdx.x]) atomicAdd(&dh[threadIdx.x], lh[threadIdx.x]);
}

__global__ void k_dscan(const int* __restrict__ dh, int* __restrict__ dcur) {
    __shared__ int s[64];
    int v = dh[threadIdx.x]; s[threadIdx.x] = v; __syncthreads();
#pragma unroll
    for (int o = 1; o < 64; o <<= 1) {
        int t = (threadIdx.x >= o) ? s[threadIdx.x - o] : 0;
        __syncthreads(); s[threadIdx.x] += t; __syncthreads();
    }
    dcur[threadIdx.x] = s[threadIdx.x] - v;   // exclusive base = start cursor
}

// v2: block-privatized scatter. R11's version did 100K global atomicAdds on
// 64 cells (263us, total serialization). Now: per-block LDS 64-bin count,
// ONE global atomicAdd per bin per block (98x64 total) to reserve a range,
// then scatter through LDS-local cursors. Block owns 1024 contiguous nodes.
__global__ __launch_bounds__(256) void k_dscat(const int* __restrict__ rs,
                                               const int* __restrict__ ce,
                                               int* __restrict__ dcur,
                                               int* __restrict__ ord, int n) {
    __shared__ int lh[64];
    __shared__ int lbase[64];
    int base = blockIdx.x * 1024;
    if (threadIdx.x < 64) lh[threadIdx.x] = 0;
    __syncthreads();
    int d[4];
#pragma unroll
    for (int k = 0; k < 4; ++k) {
        int i = base + k * 256 + threadIdx.x;
        if (i < n) {
            int dd = ce[i] - rs[i]; if (dd > 63) dd = 63;
            d[k] = dd;
            atomicAdd(&lh[dd], 1);
        } else d[k] = -1;
    }
    __syncthreads();
    if (threadIdx.x < 64) {
        int c = lh[threadIdx.x];
        lbase[threadIdx.x] = c ? atomicAdd(&dcur[threadIdx.x], c) : 0;
        lh[threadIdx.x] = 0;               // reuse as local cursor
    }
    __syncthreads();
#pragma unroll
    for (int k = 0; k < 4; ++k) {
        int i = base + k * 256 + threadIdx.x;
        if (i < n) {
            int p = atomicAdd(&lh[d[k]], 1);
            ord[lbase[d[k]] + p] = i;
        }
    }
}

// ---------------------------------------------------------------- weights
__global__ void k_aw(const void* __restrict__ W, unsigned short* __restrict__ aw,
                     const int* __restrict__ dmode, int d) {
    int idx = blockIdx.x * blockDim.x + threadIdx.x;
    if (idx >= d * d) return;
    int md = dmode[0];
    int n = idx / d, k = idx - n * d;
    float v = ldf(W, n * d + k, md) - ldf(W, k * d + n, md) - ((n == k) ? GAMMA_C : 0.0f);
    aw[idx] = f2bf(v);
}

// ---------------------------------------------------------------- GEMM v8
// (unchanged -- single-barrier pure-bf16, proven)
template<int K, int NCB, int NCF, int EPI, int NSPLIT, bool ASEL, bool BSEL>
__global__ __launch_bounds__(512) void k_gemm6(
    const void* A, const unsigned short* Acvt,
    const void* B, const unsigned short* Bcvt, const void* bias,
    unsigned short* Cout,
    const unsigned short* agg, const unsigned short* xw, const float* dinv,
    const int* dmode, void* opout, int M)
{
    constexpr int KP = K + 8;
    constexpr int NT = NCB / 16;
    constexpr int KS = K / 32;
    constexpr int SN = (NCB * K) / 4096;
    __shared__ __align__(16) unsigned short sB[NCB * KP];
    const int md = dmode[0];

    const unsigned short* Ab = (ASEL && md) ? Acvt : (const unsigned short*)A;
    const unsigned short* Bb = (BSEL && md) ? Bcvt : (const unsigned short*)B;

    const int rowblk = (NSPLIT > 1) ? ((int)blockIdx.x / NSPLIT) : (int)blockIdx.x;
    const int col0   = (NSPLIT > 1) ? ((int)blockIdx.x % NSPLIT) * NCB : 0;

    const int lane = threadIdx.x & 63;
    const int wave = threadIdx.x >> 6;
    const int l15  = lane & 15;
    const int quad = lane >> 4;
    const int row0 = rowblk * 128 + wave * 16;

    int ar = row0 + l15;
    int am = ar < M ? ar : M - 1;

    short8 a[KS];
#pragma unroll
    for (int s = 0; s < KS; ++s)
        a[s] = *(const short8*)(Ab + (size_t)am * K + s * 32 + quad * 8);

    if constexpr (SN >= 1) {
        short8 st[SN];
#pragma unroll
        for (int i = 0; i < SN; ++i) {
            int base = threadIdx.x * 8 + i * 4096;
            int r = base / K, c = base % K;
            st[i] = *(const short8*)(Bb + (size_t)(col0 + r) * K + c);
        }
#pragma unroll
        for (int i = 0; i < SN; ++i) {
            int base = threadIdx.x * 8 + i * 4096;
            int r = base / K, c = base % K;
            *(short8*)(sB + r * KP + c) = st[i];
        }
    } else {
        if (threadIdx.x < (NCB * K) / 8) {
            int base = threadIdx.x * 8;
            int r = base / K, c = base % K;
            *(short8*)(sB + r * KP + c) =
                *(const short8*)(Bb + (size_t)(col0 + r) * K + c);
        }
    }
    __builtin_amdgcn_sched_barrier(0);
    __syncthreads();

    floatx4 acc[NT];
#pragma unroll
    for (int t = 0; t < NT; ++t) acc[t] = (floatx4){0.f, 0.f, 0.f, 0.f};

#pragma unroll
    for (int s = 0; s < KS; ++s) {
        short8 b[NT];
#pragma unroll
        for (int t = 0; t < NT; ++t)
            b[t] = *(const short8*)(sB + (t * 16 + l15) * KP + s * 32 + quad * 8);
#pragma unroll
        for (int t = 0; t < NT; ++t)
            acc[t] = __builtin_amdgcn_mfma_f32_16x16x32_bf16(a[s], b[t], acc[t], 0, 0, 0);
    }

    const unsigned short* Ares = Ab;
#pragma unroll
    for (int reg = 0; reg < 4; ++reg) {
        int rr = row0 + quad * 4 + reg;
        if (EPI == 4) {
            int rrc = rr < M ? rr : M - 1;
            float dv = dinv[rrc];
            float val[NT];
#pragma unroll
            for (int t = 0; t < NT; ++t) {
                int col = t * 16 + l15;
                float z = acc[t][reg]
                        + bf2f(agg[(size_t)rrc * NCF + col])
                        + dv * bf2f(xw[(size_t)rrc * NCF + col])
                        + ldf(bias, col, md);
                val[t] = bf2f(Ares[(size_t)rrc * K + col]) + EPS_C * tanhf(z);
            }
            float m = val[0];
#pragma unroll
            for (int t = 1; t < NT; ++t) m = fmaxf(m, val[t]);
#pragma unroll
            for (int msk = 1; msk < 16; msk <<= 1) m = fmaxf(m, __shfl_xor(m, msk));
            float s = 0.f;
#pragma unroll
            for (int t = 0; t < NT; ++t) s += expf(val[t] - m);
#pragma unroll
            for (int msk = 1; msk < 16; msk <<= 1) s += __shfl_xor(s, msk);
            float ls = m + logf(s);
            if (rr < M) {
#pragma unroll
                for (int t = 0; t < NT; ++t) {
                    int col = t * 16 + l15;
                    float r = val[t] - ls;
                    if (md) ((float*)opout)[(size_t)rr * NCF + col] = r;
                    else    ((unsigned short*)opout)[(size_t)rr * NCF + col] = f2bf(r);
                }
            }
        } else {
            if (rr >= M) continue;
#pragma unroll
            for (int t = 0; t < NT; ++t) {
                int gcol = col0 + t * 16 + l15;
                float v = acc[t][reg];
                if (EPI == 0) { v += ldf(bias, gcol, md); v = v > 0.f ? v : 0.f; }
                else if (EPI == 5) { v *= dinv[rr]; }
                else if (EPI == 3) {
                    float dv = dinv[rr];
                    float z = v + bf2f(agg[(size_t)rr * NCF + gcol])
                            + dv * bf2f(xw[(size_t)rr * NCF + gcol])
                            + ldf(bias, gcol, md);
                    v = bf2f(Ares[(size_t)rr * K + gcol]) + EPS_C * tanhf(z);
                }
                Cout[(size_t)rr * NCF + gcol] = f2bf(v);
            }
        }
    }
}

// ---------------------------------------------------------------- fused lin2+phi2
__global__ __launch_bounds__(256) void k_lin2phi2(
    const unsigned short* __restrict__ A,
    const void* __restrict__ B1, const unsigned short* __restrict__ B1c,
    const void* __restrict__ bias,
    const void* __restrict__ B2, const unsigned short* __restrict__ B2c,
    unsigned short* __restrict__ h3, unsigned short* __restrict__ xws2,
    const float* __restrict__ dinv, const int* __restrict__ dmode, int M)
{
    constexpr int K1 = 128, KP1 = 136, KP2 = 40;
    __shared__ __align__(16) unsigned short sB1[32 * KP1];
    __shared__ __align__(16) unsigned short sB2[32 * KP2];
    __shared__ __align__(16) unsigned short sT[128 * KP2];
    const int md = dmode[0];

    const unsigned short* B1b = md ? B1c : (const unsigned short*)B1;
    const unsigned short* B2b = md ? B2c : (const unsigned short*)B2;

    const int lane = threadIdx.x & 63;
    const int wave = threadIdx.x >> 6;
    const int l15  = lane & 15;
    const int quad = lane >> 4;
    const int row0 = blockIdx.x * 128 + wave * 32;

    int am[2];
#pragma unroll
    for (int rt = 0; rt < 2; ++rt) {
        int r = row0 + rt * 16 + l15;
        am[rt] = r < M ? r : M - 1;
    }

    short8 a1[4][2];
#pragma unroll
    for (int s = 0; s < 4; ++s)
#pragma unroll
        for (int rt = 0; rt < 2; ++rt)
            a1[s][rt] = *(const short8*)(A + (size_t)am[rt] * K1 + s * 32 + quad * 8);

    short8 s1[2], s2;
    const bool has2 = threadIdx.x * 8 < 1024;
#pragma unroll
    for (int i = 0; i < 2; ++i)
        s1[i] = *(const short8*)(B1b + threadIdx.x * 8 + i * 2048);
    if (has2)
        s2 = *(const short8*)(B2b + threadIdx.x * 8);
#pragma unroll
    for (int i = 0; i < 2; ++i) {
        int base = threadIdx.x * 8 + i * 2048;
        int r = base / K1, c = base - r * K1;
        *(short8*)(sB1 + r * KP1 + c) = s1[i];
    }
    if (has2) {
        int base = threadIdx.x * 8;
        int r = base / 32, c = base - r * 32;
        *(short8*)(sB2 + r * KP2 + c) = s2;
    }
    __builtin_amdgcn_sched_barrier(0);
    __syncthreads();

    floatx4 acc[2][2];
#pragma unroll
    for (int rt = 0; rt < 2; ++rt) { acc[rt][0] = (floatx4){0,0,0,0}; acc[rt][1] = (floatx4){0,0,0,0}; }

#pragma unroll
    for (int s = 0; s < 4; ++s) {
#pragma unroll
        for (int rt = 0; rt < 2; ++rt) {
#pragma unroll
            for (int t = 0; t < 2; ++t) {
                short8 b = *(const short8*)(sB1 + (t * 16 + l15) * KP1 + s * 32 + quad * 8);
                acc[rt][t] = __builtin_amdgcn_mfma_f32_16x16x32_bf16(a1[s][rt], b, acc[rt][t], 0, 0, 0);
            }
        }
    }
#pragma unroll
    for (int rt = 0; rt < 2; ++rt)
#pragma unroll
        for (int reg = 0; reg < 4; ++reg) {
            int rr = row0 + rt * 16 + quad * 4 + reg;
            int lr = wave * 32 + rt * 16 + quad * 4 + reg;
#pragma unroll
            for (int t = 0; t < 2; ++t) {
                int col = t * 16 + l15;
                unsigned short hv = f2bf(acc[rt][t][reg] + ldf(bias, col, md));
                sT[lr * KP2 + col] = hv;
                if (rr < M) h3[(size_t)rr * 32 + col] = hv;
            }
        }
    __syncthreads();

    floatx4 a2[2][2];
#pragma unroll
    for (int rt = 0; rt < 2; ++rt) {
        short8 a = *(const short8*)(sT + (wave * 32 + rt * 16 + l15) * KP2 + quad * 8);
#pragma unroll
        for (int t = 0; t < 2; ++t) {
            short8 b = *(const short8*)(sB2 + (t * 16 + l15) * KP2 + quad * 8);
            a2[rt][t] = __builtin_amdgcn_mfma_f32_16x16x32_bf16(a, b, (floatx4){0,0,0,0}, 0, 0, 0);
        }
    }
#pragma unroll
    for (int rt = 0; rt < 2; ++rt)
#pragma unroll
        for (int reg = 0; reg < 4; ++reg) {
            int rr = row0 + rt * 16 + quad * 4 + reg;
            if (rr >= M) continue;
            float dv = dinv[rr];
#pragma unroll
            for (int t = 0; t < 2; ++t)
                xws2[(size_t)rr * 32 + t * 16 + l15] = f2bf(dv * a2[rt][t][reg]);
        }
}

// ---------------------------------------------------------------- gather v6
// Row-major + degree-ordered nodes (ord[]): waves are degree-uniform, so
// wide lanes carry no divergence cost. gather128: 16 lanes/node x 16B,
// 4 nodes/wave.
__global__ __launch_bounds__(256) void k_gather128(
    const int* __restrict__ srt, const int* __restrict__ rs,
    const int* __restrict__ cend, const int* __restrict__ ord,
    const unsigned short* __restrict__ xws, const float* __restrict__ dinv,
    unsigned short* __restrict__ agg, int n)
{
    int gid = blockIdx.x * 16 + (threadIdx.x >> 4);
    int l = threadIdx.x & 15;
    if (gid >= n) return;
    int node = ord[gid];
    int j = rs[node], end = cend[node];
    float ac[8] = {0.f, 0.f, 0.f, 0.f, 0.f, 0.f, 0.f, 0.f};
    int jend = j + ((end - j) & ~7);
    while (j < jend) {
        int idx[8];
#pragma unroll
        for (int k = 0; k < 8; ++k) idx[k] = srt[j + k];
        short8 p[8];
#pragma unroll
        for (int k = 0; k < 8; ++k)
            p[k] = *(const short8*)(xws + (size_t)idx[k] * 128 + l * 8);
#pragma unroll
        for (int k = 0; k < 8; ++k)
#pragma unroll
            for (int e = 0; e < 8; ++e)
                ac[e] += bf2f((unsigned short)p[k][e]);
        j += 8;
    }
    if (j < end) {
        int idx[8];
#pragma unroll
        for (int k = 0; k < 8; ++k) {
            int jj = j + k;
            idx[k] = srt[jj < end ? jj : end - 1];
        }
        short8 p[8];
#pragma unroll
        for (int k = 0; k < 8; ++k)
            p[k] = *(const short8*)(xws + (size_t)idx[k] * 128 + l * 8);
#pragma unroll
        for (int k = 0; k < 8; ++k) {
            if (j + k < end) {
#pragma unroll
                for (int e = 0; e < 8; ++e)
                    ac[e] += bf2f((unsigned short)p[k][e]);
            }
        }
    }
    float dn = dinv[node];
    short8 out;
#pragma unroll
    for (int e = 0; e < 8; ++e) out[e] = (short)f2bf(dn * ac[e]);
    *(short8*)(agg + (size_t)node * 128 + l * 8) = out;
}

// gather32 v3: 4 lanes/node x 16B, 16 nodes/wave (degree-uniform via ord).
__global__ __launch_bounds__(256) void k_gather32(
    const int* __restrict__ srt, const int* __restrict__ rs,
    const int* __restrict__ cend, const int* __restrict__ ord,
    const unsigned short* __restrict__ xws, const float* __restrict__ dinv,
    unsigned short* __restrict__ agg, int n)
{
    int gid = blockIdx.x * 64 + (threadIdx.x >> 2);
    int l = threadIdx.x & 3;
    if (gid >= n) return;
    int node = ord[gid];
    int j = rs[node], end = cend[node];
    float ac[8] = {0.f, 0.f, 0.f, 0.f, 0.f, 0.f, 0.f, 0.f};
    int jend = j + ((end - j) & ~7);
    while (j < jend) {
        int idx[8];
#pragma unroll
        for (int k = 0; k < 8; ++k) idx[k] = srt[j + k];
        short8 p[8];
#pragma unroll
        for (int k = 0; k < 8; ++k)
            p[k] = *(const short8*)(xws + (size_t)idx[k] * 32 + l * 8);
#pragma unroll
        for (int k = 0; k < 8; ++k)
#pragma unroll
            for (int e = 0; e < 8; ++e)
                ac[e] += bf2f((unsigned short)p[k][e]);
        j += 8;
    }
    if (j < end) {
        int idx[8];
#pragma unroll
        for (int k = 0; k < 8; ++k) {
            int jj = j + k;
            idx[k] = srt[jj < end ? jj : end - 1];
        }
        short8 p[8];
#pragma unroll
        for (int k = 0; k < 8; ++k)
            p[k] = *(const short8*)(xws + (size_t)idx[k] * 32 + l * 8);
#pragma unroll
        for (int k = 0; k < 8; ++k) {
            if (j + k < end) {
#pragma unroll
                for (int e = 0; e < 8; ++e)
                    ac[e] += bf2f((unsigned short)p[k][e]);
            }
        }
    }
    float dn = dinv[node];
    short8 out;
#pragma unroll
    for (int e = 0; e < 8; ++e) out[e] = (short)f2bf(dn * ac[e]);
    *(short8*)(agg + (size_t)node * 32 + l * 8) = out;
}

// ---------------------------------------------------------------- launch
extern "C" void kernel_launch(void* const* d_in, const int* in_sizes, int n_in,
                              void* d_out, int out_size, void* d_ws, size_t ws_size,
                              hipStream_t stream)
{
    const void* x      = d_in[0];
    const void* lin1_w = d_in[1];
    const void* lin1_b = d_in[2];
    const void* lin2_w = d_in[3];
    const void* lin2_b = d_in[4];
    const void* W1     = d_in[5];
    const void* phi1w  = d_in[6];
    const void* b1     = d_in[7];
    const void* W2     = d_in[8];
    const void* phi2w  = d_in[9];
    const void* b2     = d_in[10];
    const int* eidx    = (const int*)d_in[11];
    const int* erow = eidx;
    const int* ecol = eidx + NEDGES;

    // Workspace (high-water ~87.7 MB; ord/dh appended after agg1 span)
    char* ws = (char*)d_ws;
    float* dinv          = (float*)ws;                    // [N] f32
    int*   dmode         = (int*)(ws + 400000);
    unsigned short* aw1  = (unsigned short*)(ws + 401408);
    unsigned short* aw2  = (unsigned short*)(ws + 435200);
    int* tot             = (int*)(ws + 440320);           // [782]
    int* bbase           = (int*)(ws + 443648);           // [782]
    int* row_start       = (int*)(ws + 446976);           // [N]
    int* cend            = (int*)(ws + 846976);           // [N]
    int* srt             = (int*)(ws + 1246976);          // [E] 6.4MB
    int* hist            = (int*)(ws + 7646976);          // [NCH*NBK]
    int* offb            = (int*)(ws + 8870912);          // [NCH*NBK] ends 10093960
    unsigned short* wbf  = (unsigned short*)(ws + 10094080); // 108.5KB, in the gap
    unsigned short* h1   = (unsigned short*)(ws + 10485760);          // [N,128]
    unsigned short* xws1 = h1 + (size_t)N_NODES * HID;                // [N,128]
    unsigned short* agg1 = xws1 + (size_t)N_NODES * HID;              // [N,128]
    unsigned short* h2   = xws1;   // EPI3 in-place (read-before-write per thread)
    unsigned short* h3   = h1;     // h1 dead after EPI3
    unsigned short* xws2 = agg1;   // agg1 dead after EPI3
    unsigned short* agg2 = agg1 + (size_t)N_NODES * NCLS;
    unsigned int* pairs  = (unsigned int*)agg1;  // consumed by k_build before cvtx
    unsigned short* xbf  = xws1;   // [N,256] bf16 = xws1+agg1 span; dead after lin1
    int* ord             = (int*)(ws + 87285760);         // [N] after agg1 span
    int* dh              = (int*)(ws + 87685760);         // [64]
    int* dcur            = dh + 64;                       // [64]

    // converted-weight segments (elems): lin1_w 32768 | phi1w 16384 | lin2_w 4096 | phi2w 1024
    unsigned short* bw1 = wbf;
    unsigned short* bp1 = wbf + 32768;
    unsigned short* bw2 = wbf + 49152;
    unsigned short* bp2 = wbf + 53248;

    const int GB = 256;
    const int NB5 = (N_NODES + 127) / 128;     // 782 blocks (128 rows/block, 8 waves)
    k_detect<<<1, 256, 0, stream>>>((const unsigned short*)x, dmode);

    // CSR build v3: radix partition, zero global atomics
    k_hist2<<<NCH, 256, 0, stream>>>(ecol, hist, NEDGES);
    k_tot<<<NBK, 256, 0, stream>>>(hist, tot);
    k_bscan<<<1, 1024, 0, stream>>>(tot, bbase);
    k_colscan<<<NBK, 512, 0, stream>>>(hist, bbase, offb);
    k_pass3<<<NCH, 256, 0, stream>>>(erow, ecol, offb, pairs, NEDGES);
    k_build<<<NBK, 256, 0, stream>>>(tot, bbase, pairs, srt, row_start, cend, dinv, N_NODES);

    // degree-sorted node order for the gathers (block-privatized scatter)
    k_dzero<<<1, 64, 0, stream>>>(dh);
    k_dhist<<<98, 256, 0, stream>>>(row_start, cend, dh, N_NODES);
    k_dscan<<<1, 64, 0, stream>>>(dh, dcur);
    k_dscat<<<(N_NODES + 1023) / 1024, 256, 0, stream>>>(row_start, cend, dcur, ord, N_NODES);

    // antisymmetric weights + bf16 pre-conversion
    k_aw<<<(HID * HID + GB - 1) / GB, GB, 0, stream>>>(W1, aw1, dmode, HID);
    k_aw<<<(NCLS * NCLS + GB - 1) / GB, GB, 0, stream>>>(W2, aw2, dmode, NCLS);
    k_cvtw<<<27, 256, 0, stream>>>(lin1_w, phi1w, lin2_w, phi2w, wbf, dmode);
    k_cvtx<<<2048, 256, 0, stream>>>(x, xbf, dmode, N_NODES * F_IN / 8);

    // h1 = relu(x @ lin1_w.T + lin1_b)   col-split x2 (33.8KB LDS), bf16 path
    k_gemm6<256, 64, 128, 0, 2, true, true><<<NB5 * 2, 512, 0, stream>>>(
        x, xbf, lin1_w, bw1, lin1_b, h1, nullptr, nullptr, nullptr, dmode, nullptr, N_NODES);
    // xws1 = dinv * (h1 @ phi1_w.T)      full B in LDS (34.8KB), one barrier
    k_gemm6<128, 128, 128, 5, 1, false, true><<<NB5, 512, 0, stream>>>(
        h1, nullptr, phi1w, bp1, nullptr, xws1, nullptr, nullptr, dinv, dmode, nullptr, N_NODES);
    // agg1 = dinv * gather(xws1)         degree-ordered
    k_gather128<<<(N_NODES + 15) / 16, 256, 0, stream>>>(
        srt, row_start, cend, ord, xws1, dinv, agg1, N_NODES);
    // h2 = h1 + EPS*tanh(h1@aw1.T + agg1 + dinv*xws1 + b1)   (in-place on xws1)
    k_gemm6<128, 128, 128, 3, 1, false, false><<<NB5, 512, 0, stream>>>(
        h1, nullptr, aw1, nullptr, b1, h2, agg1, xws1, dinv, dmode, nullptr, N_NODES);
    // h3 = h2@lin2_w.T + lin2_b ; xws2 = dinv*(h3@phi2_w.T)   (fused)
    k_lin2phi2<<<(N_NODES + 127) / 128, 256, 0, stream>>>(
        h2, lin2_w, bw2, lin2_b, phi2w, bp2, h3, xws2, dinv, dmode, N_NODES);
    // agg2 = dinv * gather(xws2)         degree-ordered
    k_gather32<<<(N_NODES + 63) / 64, 256, 0, stream>>>(
        srt, row_start, cend, ord, xws2, dinv, agg2, N_NODES);
    // out = log_softmax(h3 + EPS*tanh(h3@aw2.T + agg2 + dinv*xws2 + b2))  (fused)
    k_gemm6<32, 32, 32, 4, 1, false, false><<<NB5, 512, 0, stream>>>(
        h3, nullptr, aw2, nullptr, b2, nullptr, agg2, xws2, dinv, dmode, d_out, N_NODES);
}

// Round 13
// 416.920 us; speedup vs baseline: 1.6738x; 1.0424x over previous
//
#include <hip/hip_runtime.h>
#include <hip/hip_bf16.h>
#include <math.h>

// Problem constants (from reference)
#define N_NODES 100000
#define F_IN    256
#define HID     128
#define NCLS    32
#define NEDGES  1600000
#define EPS_C   0.1f
#define GAMMA_C 0.1f

// CSR build: radix partition into 782 buckets of 128 nodes, no global atomics
#define NBK   782                  // ceil(100000/128)
#define CHUNK 4096
#define NCH   391                  // ceil(1600000/4096)
#define BMAX  4096                 // bucket cap for k_build LDS (mean 2046, +45 sigma)

typedef __attribute__((ext_vector_type(8))) short short8;   // 8 bf16 = 4 VGPRs (MFMA A/B frag)
typedef __attribute__((ext_vector_type(4))) float floatx4;  // MFMA C/D frag

__device__ __forceinline__ float bf2f(unsigned short u) {
    union { unsigned int u; float f; } c;
    c.u = ((unsigned int)u) << 16;
    return c.f;
}
__device__ __forceinline__ unsigned short f2bf(float f) {
    union { float f; unsigned int u; } c; c.f = f;
    unsigned int u = c.u;
    u += 0x7FFFu + ((u >> 16) & 1u);   // round-to-nearest-even
    return (unsigned short)(u >> 16);
}

__device__ __forceinline__ short8 cvt8(float4 u, float4 v) {
    short8 r;
    r[0] = (short)f2bf(u.x); r[1] = (short)f2bf(u.y);
    r[2] = (short)f2bf(u.z); r[3] = (short)f2bf(u.w);
    r[4] = (short)f2bf(v.x); r[5] = (short)f2bf(v.y);
    r[6] = (short)f2bf(v.z); r[7] = (short)f2bf(v.w);
    return r;
}

// Polymorphic scalar load: md=1 -> buffer is f32, md=0 -> bf16 (epilogue bias only)
__device__ __forceinline__ float ldf(const void* p, size_t i, int md) {
    return md ? ((const float*)p)[i] : bf2f(((const unsigned short*)p)[i]);
}

// ---------------------------------------------------------------- dtype probe
__global__ void k_detect(const unsigned short* __restrict__ x, int* __restrict__ mode) {
    __shared__ int cnt;
    if (threadIdx.x == 0) cnt = 0;
    __syncthreads();
    float v = fabsf(bf2f(x[2 * threadIdx.x]));
    if (v > 1e4f || !isfinite(v)) atomicAdd(&cnt, 1);
    __syncthreads();
    if (threadIdx.x == 0) *mode = (cnt >= 8) ? 1 : 0;
}

// ---------------------------------------------------------------- pre-convert
__global__ __launch_bounds__(256) void k_cvtx(const void* __restrict__ x,
                                              unsigned short* __restrict__ xbf,
                                              const int* __restrict__ dmode, int n8) {
    if (!dmode[0]) return;
    const float* xf = (const float*)x;
    int stride = gridDim.x * 256;
    for (int i = blockIdx.x * 256 + threadIdx.x; i < n8; i += stride) {
        const float* q = xf + (size_t)i * 8;
        float4 u = *(const float4*)q, v = *(const float4*)(q + 4);
        *(short8*)(xbf + (size_t)i * 8) = cvt8(u, v);
    }
}

// Weight matrices f32 -> bf16 into one contiguous buffer.
__global__ __launch_bounds__(256) void k_cvtw(const void* __restrict__ w1,
                                              const void* __restrict__ w2,
                                              const void* __restrict__ w3,
                                              const void* __restrict__ w4,
                                              unsigned short* __restrict__ out,
                                              const int* __restrict__ dmode) {
    if (!dmode[0]) return;
    int i = blockIdx.x * 256 + threadIdx.x;     // 8-elem group index
    const float* src; int off;
    if (i < 4096)      { src = (const float*)w1; off = i; }
    else if (i < 6144) { src = (const float*)w2; off = i - 4096; }
    else if (i < 6656) { src = (const float*)w3; off = i - 6144; }
    else if (i < 6784) { src = (const float*)w4; off = i - 6656; }
    else return;
    const float* q = src + (size_t)off * 8;
    *(short8*)(out + (size_t)i * 8) = cvt8(*(const float4*)q, *(const float4*)(q + 4));
}

// ---------------------------------------------------------------- CSR build v3
__global__ __launch_bounds__(256) void k_hist2(const int* __restrict__ ecol,
                                               int* __restrict__ hist, int e) {
    __shared__ int lh[NBK];
    for (int i = threadIdx.x; i < NBK; i += 256) lh[i] = 0;
    __syncthreads();
    int base = blockIdx.x * CHUNK;
    int lim = base + CHUNK; if (lim > e) lim = e;
    for (int i = base + threadIdx.x; i < lim; i += 256)
        atomicAdd(&lh[ecol[i] >> 7], 1);
    __syncthreads();
    for (int i = threadIdx.x; i < NBK; i += 256) hist[blockIdx.x * NBK + i] = lh[i];
}

__global__ __launch_bounds__(256) void k_tot(const int* __restrict__ hist, int* __restrict__ tot) {
    __shared__ int s[256];
    int b = blockIdx.x;
    int v = 0;
    for (int blk = threadIdx.x; blk < NCH; blk += 256) v += hist[blk * NBK + b];
    s[threadIdx.x] = v;
    __syncthreads();
#pragma unroll
    for (int off = 128; off > 0; off >>= 1) {
        if (threadIdx.x < off) s[threadIdx.x] += s[threadIdx.x + off];
        __syncthreads();
    }
    if (threadIdx.x == 0) tot[b] = s[0];
}

__global__ void k_bscan(const int* __restrict__ tot, int* __restrict__ bbase) {
    __shared__ int s[1024];
    int v = (threadIdx.x < NBK) ? tot[threadIdx.x] : 0;
    s[threadIdx.x] = v;
    __syncthreads();
#pragma unroll
    for (int off = 1; off < 1024; off <<= 1) {
        int t = (threadIdx.x >= off) ? s[threadIdx.x - off] : 0;
        __syncthreads();
        s[threadIdx.x] += t;
        __syncthreads();
    }
    if (threadIdx.x < NBK) bbase[threadIdx.x] = s[threadIdx.x] - v;
}

__global__ __launch_bounds__(512) void k_colscan(const int* __restrict__ hist,
                                                 const int* __restrict__ bbase,
                                                 int* __restrict__ off) {
    __shared__ int s[512];
    int b = blockIdx.x, t = threadIdx.x;
    int v = (t < NCH) ? hist[t * NBK + b] : 0;
    s[t] = v;
    __syncthreads();
#pragma unroll
    for (int o = 1; o < 512; o <<= 1) {
        int u = (t >= o) ? s[t - o] : 0;
        __syncthreads();
        s[t] += u;
        __syncthreads();
    }
    if (t < NCH) off[t * NBK + b] = s[t] - v + bbase[b];
}

// sbk[] records each edge's bucket during the scatter -> the final
// placement loop does ONE LDS read instead of a 10-step binary search.
__global__ __launch_bounds__(256) void k_pass3(
    const int* __restrict__ erow, const int* __restrict__ ecol,
    const int* __restrict__ off, unsigned int* __restrict__ pairs, int e)
{
    __shared__ int lh[NBK];
    __shared__ int lex[NBK];
    __shared__ int cur[NBK];
    __shared__ int wsum[256];
    __shared__ unsigned int sp[CHUNK];
    __shared__ unsigned short sbk[CHUNK];
    int base = blockIdx.x * CHUNK;
    int lim = base + CHUNK; if (lim > e) lim = e;
    int cnt = lim - base;

    for (int i = threadIdx.x; i < NBK; i += 256) lh[i] = 0;
    __syncthreads();
    for (int i = base + threadIdx.x; i < lim; i += 256)
        atomicAdd(&lh[ecol[i] >> 7], 1);
    __syncthreads();

    int t4 = threadIdx.x * 4;
    int a0 = (t4 + 0 < NBK) ? lh[t4 + 0] : 0;
    int a1 = (t4 + 1 < NBK) ? lh[t4 + 1] : 0;
    int a2 = (t4 + 2 < NBK) ? lh[t4 + 2] : 0;
    int a3 = (t4 + 3 < NBK) ? lh[t4 + 3] : 0;
    int mysum = a0 + a1 + a2 + a3;
    wsum[threadIdx.x] = mysum;
    __syncthreads();
#pragma unroll
    for (int o = 1; o < 256; o <<= 1) {
        int u = (threadIdx.x >= o) ? wsum[threadIdx.x - o] : 0;
        __syncthreads();
        wsum[threadIdx.x] += u;
        __syncthreads();
    }
    int run = wsum[threadIdx.x] - mysum;
    if (t4 + 0 < NBK) { lex[t4 + 0] = run;            cur[t4 + 0] = run; }
    if (t4 + 1 < NBK) { lex[t4 + 1] = run + a0;       cur[t4 + 1] = run + a0; }
    if (t4 + 2 < NBK) { lex[t4 + 2] = run + a0 + a1;  cur[t4 + 2] = run + a0 + a1; }
    if (t4 + 3 < NBK) { lex[t4 + 3] = run + a0 + a1 + a2; cur[t4 + 3] = run + a0 + a1 + a2; }
    __syncthreads();

    for (int i = base + threadIdx.x; i < lim; i += 256) {
        int dst = ecol[i], src = erow[i];
        int b = dst >> 7;
        int p = atomicAdd(&cur[b], 1);
        sp[p] = ((unsigned int)src << 7) | (unsigned int)(dst & 127);
        sbk[p] = (unsigned short)b;
    }
    __syncthreads();

    for (int i = threadIdx.x; i < cnt; i += 256) {
        int b = sbk[i];
        pairs[off[blockIdx.x * NBK + b] + (i - lex[b])] = sp[i];
    }
}

__global__ __launch_bounds__(256) void k_build(
    const int* __restrict__ tot, const int* __restrict__ bbase,
    const unsigned int* __restrict__ pairs,
    int* __restrict__ srt, int* __restrict__ row_start, int* __restrict__ cend,
    float* __restrict__ dinv, int n)
{
    __shared__ int lh[128];
    __shared__ int lo[128];
    __shared__ unsigned int se[BMAX];
    int b = blockIdx.x;
    int nb = tot[b]; if (nb > BMAX) nb = BMAX;
    int base = bbase[b];
    if (threadIdx.x < 128) lh[threadIdx.x] = 0;
    __syncthreads();
    for (int e = threadIdx.x; e < nb; e += 256) {
        unsigned int pk = pairs[(size_t)base + e];
        se[e] = pk;
        atomicAdd(&lh[pk & 127u], 1);
    }
    __syncthreads();
    if (threadIdx.x < 128) lo[threadIdx.x] = lh[threadIdx.x];
    __syncthreads();
#pragma unroll
    for (int off = 1; off < 128; off <<= 1) {
        int t = (threadIdx.x < 128 && threadIdx.x >= off) ? lo[threadIdx.x - off] : 0;
        __syncthreads();
        if (threadIdx.x < 128) lo[threadIdx.x] += t;
        __syncthreads();
    }
    int node = b * 128 + threadIdx.x;
    if (threadIdx.x < 128 && node < n) {
        int inc = lo[threadIdx.x], cnt = lh[threadIdx.x];
        row_start[node] = base + inc - cnt;
        cend[node]      = base + inc;
        dinv[node]      = rsqrtf((float)cnt + 1.0f);
    }
    __syncthreads();
    if (threadIdx.x < 128) lh[threadIdx.x] = lo[threadIdx.x] - lh[threadIdx.x];
    __syncthreads();
    for (int e = threadIdx.x; e < nb; e += 256) {
        unsigned int pk = se[e];
        int pos = atomicAdd(&lh[pk & 127u], 1);
        srt[base + pos] = (int)(pk >> 7);
    }
}

// ---------------------------------------------------------------- weights
__global__ void k_aw(const void* __restrict__ W, unsigned short* __restrict__ aw,
                     const int* __restrict__ dmode, int d) {
    int idx = blockIdx.x * blockDim.x + threadIdx.x;
    if (idx >= d * d) return;
    int md = dmode[0];
    int n = idx / d, k = idx - n * d;
    float v = ldf(W, n * d + k, md) - ldf(W, k * d + n, md) - ((n == k) ? GAMMA_C : 0.0f);
    aw[idx] = f2bf(v);
}

// ---------------------------------------------------------------- GEMM v8
// (single-barrier pure-bf16, proven R10 config)
template<int K, int NCB, int NCF, int EPI, int NSPLIT, bool ASEL, bool BSEL>
__global__ __launch_bounds__(512) void k_gemm6(
    const void* A, const unsigned short* Acvt,
    const void* B, const unsigned short* Bcvt, const void* bias,
    unsigned short* Cout,
    const unsigned short* agg, const unsigned short* xw, const float* dinv,
    const int* dmode, void* opout, int M)
{
    constexpr int KP = K + 8;
    constexpr int NT = NCB / 16;
    constexpr int KS = K / 32;
    constexpr int SN = (NCB * K) / 4096;
    __shared__ __align__(16) unsigned short sB[NCB * KP];
    const int md = dmode[0];

    const unsigned short* Ab = (ASEL && md) ? Acvt : (const unsigned short*)A;
    const unsigned short* Bb = (BSEL && md) ? Bcvt : (const unsigned short*)B;

    const int rowblk = (NSPLIT > 1) ? ((int)blockIdx.x / NSPLIT) : (int)blockIdx.x;
    const int col0   = (NSPLIT > 1) ? ((int)blockIdx.x % NSPLIT) * NCB : 0;

    const int lane = threadIdx.x & 63;
    const int wave = threadIdx.x >> 6;
    const int l15  = lane & 15;
    const int quad = lane >> 4;
    const int row0 = rowblk * 128 + wave * 16;

    int ar = row0 + l15;
    int am = ar < M ? ar : M - 1;

    short8 a[KS];
#pragma unroll
    for (int s = 0; s < KS; ++s)
        a[s] = *(const short8*)(Ab + (size_t)am * K + s * 32 + quad * 8);

    if constexpr (SN >= 1) {
        short8 st[SN];
#pragma unroll
        for (int i = 0; i < SN; ++i) {
            int base = threadIdx.x * 8 + i * 4096;
            int r = base / K, c = base % K;
            st[i] = *(const short8*)(Bb + (size_t)(col0 + r) * K + c);
        }
#pragma unroll
        for (int i = 0; i < SN; ++i) {
            int base = threadIdx.x * 8 + i * 4096;
            int r = base / K, c = base % K;
            *(short8*)(sB + r * KP + c) = st[i];
        }
    } else {
        if (threadIdx.x < (NCB * K) / 8) {
            int base = threadIdx.x * 8;
            int r = base / K, c = base % K;
            *(short8*)(sB + r * KP + c) =
                *(const short8*)(Bb + (size_t)(col0 + r) * K + c);
        }
    }
    __builtin_amdgcn_sched_barrier(0);
    __syncthreads();

    floatx4 acc[NT];
#pragma unroll
    for (int t = 0; t < NT; ++t) acc[t] = (floatx4){0.f, 0.f, 0.f, 0.f};

#pragma unroll
    for (int s = 0; s < KS; ++s) {
        short8 b[NT];
#pragma unroll
        for (int t = 0; t < NT; ++t)
            b[t] = *(const short8*)(sB + (t * 16 + l15) * KP + s * 32 + quad * 8);
#pragma unroll
        for (int t = 0; t < NT; ++t)
            acc[t] = __builtin_amdgcn_mfma_f32_16x16x32_bf16(a[s], b[t], acc[t], 0, 0, 0);
    }

    const unsigned short* Ares = Ab;
#pragma unroll
    for (int reg = 0; reg < 4; ++reg) {
        int rr = row0 + quad * 4 + reg;
        if (EPI == 4) {
            int rrc = rr < M ? rr : M - 1;
            float dv = dinv[rrc];
            float val[NT];
#pragma unroll
            for (int t = 0; t < NT; ++t) {
                int col = t * 16 + l15;
                float z = acc[t][reg]
                        + bf2f(agg[(size_t)rrc * NCF + col])
                        + dv * bf2f(xw[(size_t)rrc * NCF + col])
                        + ldf(bias, col, md);
                val[t] = bf2f(Ares[(size_t)rrc * K + col]) + EPS_C * tanhf(z);
            }
            float m = val[0];
#pragma unroll
            for (int t = 1; t < NT; ++t) m = fmaxf(m, val[t]);
#pragma unroll
            for (int msk = 1; msk < 16; msk <<= 1) m = fmaxf(m, __shfl_xor(m, msk));
            float s = 0.f;
#pragma unroll
            for (int t = 0; t < NT; ++t) s += expf(val[t] - m);
#pragma unroll
            for (int msk = 1; msk < 16; msk <<= 1) s += __shfl_xor(s, msk);
            float ls = m + logf(s);
            if (rr < M) {
#pragma unroll
                for (int t = 0; t < NT; ++t) {
                    int col = t * 16 + l15;
                    float r = val[t] - ls;
                    if (md) ((float*)opout)[(size_t)rr * NCF + col] = r;
                    else    ((unsigned short*)opout)[(size_t)rr * NCF + col] = f2bf(r);
                }
            }
        } else {
            if (rr >= M) continue;
#pragma unroll
            for (int t = 0; t < NT; ++t) {
                int gcol = col0 + t * 16 + l15;
                float v = acc[t][reg];
                if (EPI == 0) { v += ldf(bias, gcol, md); v = v > 0.f ? v : 0.f; }
                else if (EPI == 5) { v *= dinv[rr]; }
                else if (EPI == 3) {
                    float dv = dinv[rr];
                    float z = v + bf2f(agg[(size_t)rr * NCF + gcol])
                            + dv * bf2f(xw[(size_t)rr * NCF + gcol])
                            + ldf(bias, gcol, md);
                    v = bf2f(Ares[(size_t)rr * K + gcol]) + EPS_C * tanhf(z);
                }
                Cout[(size_t)rr * NCF + gcol] = f2bf(v);
            }
        }
    }
}

// ---------------------------------------------------------------- fused lin2+phi2
__global__ __launch_bounds__(256) void k_lin2phi2(
    const unsigned short* __restrict__ A,
    const void* __restrict__ B1, const unsigned short* __restrict__ B1c,
    const void* __restrict__ bias,
    const void* __restrict__ B2, const unsigned short* __restrict__ B2c,
    unsigned short* __restrict__ h3, unsigned short* __restrict__ xws2,
    const float* __restrict__ dinv, const int* __restrict__ dmode, int M)
{
    constexpr int K1 = 128, KP1 = 136, KP2 = 40;
    __shared__ __align__(16) unsigned short sB1[32 * KP1];
    __shared__ __align__(16) unsigned short sB2[32 * KP2];
    __shared__ __align__(16) unsigned short sT[128 * KP2];
    const int md = dmode[0];

    const unsigned short* B1b = md ? B1c : (const unsigned short*)B1;
    const unsigned short* B2b = md ? B2c : (const unsigned short*)B2;

    const int lane = threadIdx.x & 63;
    const int wave = threadIdx.x >> 6;
    const int l15  = lane & 15;
    const int quad = lane >> 4;
    const int row0 = blockIdx.x * 128 + wave * 32;

    int am[2];
#pragma unroll
    for (int rt = 0; rt < 2; ++rt) {
        int r = row0 + rt * 16 + l15;
        am[rt] = r < M ? r : M - 1;
    }

    short8 a1[4][2];
#pragma unroll
    for (int s = 0; s < 4; ++s)
#pragma unroll
        for (int rt = 0; rt < 2; ++rt)
            a1[s][rt] = *(const short8*)(A + (size_t)am[rt] * K1 + s * 32 + quad * 8);

    short8 s1[2], s2;
    const bool has2 = threadIdx.x * 8 < 1024;
#pragma unroll
    for (int i = 0; i < 2; ++i)
        s1[i] = *(const short8*)(B1b + threadIdx.x * 8 + i * 2048);
    if (has2)
        s2 = *(const short8*)(B2b + threadIdx.x * 8);
#pragma unroll
    for (int i = 0; i < 2; ++i) {
        int base = threadIdx.x * 8 + i * 2048;
        int r = base / K1, c = base - r * K1;
        *(short8*)(sB1 + r * KP1 + c) = s1[i];
    }
    if (has2) {
        int base = threadIdx.x * 8;
        int r = base / 32, c = base - r * 32;
        *(short8*)(sB2 + r * KP2 + c) = s2;
    }
    __builtin_amdgcn_sched_barrier(0);
    __syncthreads();

    floatx4 acc[2][2];
#pragma unroll
    for (int rt = 0; rt < 2; ++rt) { acc[rt][0] = (floatx4){0,0,0,0}; acc[rt][1] = (floatx4){0,0,0,0}; }

#pragma unroll
    for (int s = 0; s < 4; ++s) {
#pragma unroll
        for (int rt = 0; rt < 2; ++rt) {
#pragma unroll
            for (int t = 0; t < 2; ++t) {
                short8 b = *(const short8*)(sB1 + (t * 16 + l15) * KP1 + s * 32 + quad * 8);
                acc[rt][t] = __builtin_amdgcn_mfma_f32_16x16x32_bf16(a1[s][rt], b, acc[rt][t], 0, 0, 0);
            }
        }
    }
#pragma unroll
    for (int rt = 0; rt < 2; ++rt)
#pragma unroll
        for (int reg = 0; reg < 4; ++reg) {
            int rr = row0 + rt * 16 + quad * 4 + reg;
            int lr = wave * 32 + rt * 16 + quad * 4 + reg;
#pragma unroll
            for (int t = 0; t < 2; ++t) {
                int col = t * 16 + l15;
                unsigned short hv = f2bf(acc[rt][t][reg] + ldf(bias, col, md));
                sT[lr * KP2 + col] = hv;
                if (rr < M) h3[(size_t)rr * 32 + col] = hv;
            }
        }
    __syncthreads();

    floatx4 a2[2][2];
#pragma unroll
    for (int rt = 0; rt < 2; ++rt) {
        short8 a = *(const short8*)(sT + (wave * 32 + rt * 16 + l15) * KP2 + quad * 8);
#pragma unroll
        for (int t = 0; t < 2; ++t) {
            short8 b = *(const short8*)(sB2 + (t * 16 + l15) * KP2 + quad * 8);
            a2[rt][t] = __builtin_amdgcn_mfma_f32_16x16x32_bf16(a, b, (floatx4){0,0,0,0}, 0, 0, 0);
        }
    }
#pragma unroll
    for (int rt = 0; rt < 2; ++rt)
#pragma unroll
        for (int reg = 0; reg < 4; ++reg) {
            int rr = row0 + rt * 16 + quad * 4 + reg;
            if (rr >= M) continue;
            float dv = dinv[rr];
#pragma unroll
            for (int t = 0; t < 2; ++t)
                xws2[(size_t)rr * 32 + t * 16 + l15] = f2bf(dv * a2[rt][t][reg]);
        }
}

// ---------------------------------------------------------------- gather v5 (R10 proven)
// Row-major, 32 lanes/node x uint2; guard-free full batches of 8 + guarded
// tail. Measured 61-62us = aggregate random-256B-row bandwidth floor
// (slice-pinning R8/R9 and degree-sorting R11/R12 both failed to beat it).
__global__ __launch_bounds__(256) void k_gather128(
    const int* __restrict__ srt, const int* __restrict__ rs,
    const int* __restrict__ cend,
    const unsigned short* __restrict__ xws, const float* __restrict__ dinv,
    unsigned short* __restrict__ agg, int n)
{
    int node = blockIdx.x * 8 + (threadIdx.x >> 5);
    int l = threadIdx.x & 31;
    if (node >= n) return;
    int j = rs[node], end = cend[node];
    float a0 = 0.f, a1 = 0.f, a2 = 0.f, a3 = 0.f;
    int jend = j + ((end - j) & ~7);
    while (j < jend) {
        int idx[8];
#pragma unroll
        for (int k = 0; k < 8; ++k) idx[k] = srt[j + k];
        uint2 p[8];
#pragma unroll
        for (int k = 0; k < 8; ++k)
            p[k] = *(const uint2*)(xws + (size_t)idx[k] * 128 + l * 4);
#pragma unroll
        for (int k = 0; k < 8; ++k) {
            a0 += bf2f((unsigned short)(p[k].x & 0xFFFFu));
            a1 += bf2f((unsigned short)(p[k].x >> 16));
            a2 += bf2f((unsigned short)(p[k].y & 0xFFFFu));
            a3 += bf2f((unsigned short)(p[k].y >> 16));
        }
        j += 8;
    }
    if (j < end) {
        int idx[8];
#pragma unroll
        for (int k = 0; k < 8; ++k) {
            int jj = j + k;
            idx[k] = srt[jj < end ? jj : end - 1];
        }
        uint2 p[8];
#pragma unroll
        for (int k = 0; k < 8; ++k)
            p[k] = *(const uint2*)(xws + (size_t)idx[k] * 128 + l * 4);
#pragma unroll
        for (int k = 0; k < 8; ++k) {
            if (j + k < end) {
                a0 += bf2f((unsigned short)(p[k].x & 0xFFFFu));
                a1 += bf2f((unsigned short)(p[k].x >> 16));
                a2 += bf2f((unsigned short)(p[k].y & 0xFFFFu));
                a3 += bf2f((unsigned short)(p[k].y >> 16));
            }
        }
    }
    float dn = dinv[node];
    uint2 out;
    out.x = (unsigned int)f2bf(dn * a0) | ((unsigned int)f2bf(dn * a1) << 16);
    out.y = (unsigned int)f2bf(dn * a2) | ((unsigned int)f2bf(dn * a3) << 16);
    *(uint2*)(agg + (size_t)node * 128 + l * 4) = out;
}

// gather32 (R10 proven): 8 lanes/node x uint2, guard-free main loop.
__global__ __launch_bounds__(256) void k_gather32(
    const int* __restrict__ srt, const int* __restrict__ rs,
    const int* __restrict__ cend,
    const unsigned short* __restrict__ xws, const float* __restrict__ dinv,
    unsigned short* __restrict__ agg, int n)
{
    int node = blockIdx.x * 32 + (threadIdx.x >> 3);
    int l = threadIdx.x & 7;
    if (node >= n) return;
    int j = rs[node], end = cend[node];
    float a0 = 0.f, a1 = 0.f, a2 = 0.f, a3 = 0.f;
    int jend = j + ((end - j) & ~7);
    while (j < jend) {
        int idx[8];
#pragma unroll
        for (int k = 0; k < 8; ++k) idx[k] = srt[j + k];
        uint2 p[8];
#pragma unroll
        for (int k = 0; k < 8; ++k)
            p[k] = *(const uint2*)(xws + (size_t)idx[k] * 32 + l * 4);
#pragma unroll
        for (int k = 0; k < 8; ++k) {
            a0 += bf2f((unsigned short)(p[k].x & 0xFFFFu));
            a1 += bf2f((unsigned short)(p[k].x >> 16));
            a2 += bf2f((unsigned short)(p[k].y & 0xFFFFu));
            a3 += bf2f((unsigned short)(p[k].y >> 16));
        }
        j += 8;
    }
    if (j < end) {
        int idx[8];
#pragma unroll
        for (int k = 0; k < 8; ++k) {
            int jj = j + k;
            idx[k] = srt[jj < end ? jj : end - 1];
        }
        uint2 p[8];
#pragma unroll
        for (int k = 0; k < 8; ++k)
            p[k] = *(const uint2*)(xws + (size_t)idx[k] * 32 + l * 4);
#pragma unroll
        for (int k = 0; k < 8; ++k) {
            if (j + k < end) {
                a0 += bf2f((unsigned short)(p[k].x & 0xFFFFu));
                a1 += bf2f((unsigned short)(p[k].x >> 16));
                a2 += bf2f((unsigned short)(p[k].y & 0xFFFFu));
                a3 += bf2f((unsigned short)(p[k].y >> 16));
            }
        }
    }
    float dn = dinv[node];
    uint2 out;
    out.x = (unsigned int)f2bf(dn * a0) | ((unsigned int)f2bf(dn * a1) << 16);
    out.y = (unsigned int)f2bf(dn * a2) | ((unsigned int)f2bf(dn * a3) << 16);
    *(uint2*)(agg + (size_t)node * 32 + l * 4) = out;
}

// ---------------------------------------------------------------- launch
extern "C" void kernel_launch(void* const* d_in, const int* in_sizes, int n_in,
                              void* d_out, int out_size, void* d_ws, size_t ws_size,
                              hipStream_t stream)
{
    const void* x      = d_in[0];
    const void* lin1_w = d_in[1];
    const void* lin1_b = d_in[2];
    const void* lin2_w = d_in[3];
    const void* lin2_b = d_in[4];
    const void* W1     = d_in[5];
    const void* phi1w  = d_in[6];
    const void* b1     = d_in[7];
    const void* W2     = d_in[8];
    const void* phi2w  = d_in[9];
    const void* b2     = d_in[10];
    const int* eidx    = (const int*)d_in[11];
    const int* erow = eidx;
    const int* ecol = eidx + NEDGES;

    // Workspace (high-water ~87.3 MB; xbf aliases xws1+agg1)
    char* ws = (char*)d_ws;
    float* dinv          = (float*)ws;                    // [N] f32
    int*   dmode         = (int*)(ws + 400000);
    unsigned short* aw1  = (unsigned short*)(ws + 401408);
    unsigned short* aw2  = (unsigned short*)(ws + 435200);
    int* tot             = (int*)(ws + 440320);           // [782]
    int* bbase           = (int*)(ws + 443648);           // [782]
    int* row_start       = (int*)(ws + 446976);           // [N]
    int* cend            = (int*)(ws + 846976);           // [N]
    int* srt             = (int*)(ws + 1246976);          // [E] 6.4MB
    int* hist            = (int*)(ws + 7646976);          // [NCH*NBK]
    int* offb            = (int*)(ws + 8870912);          // [NCH*NBK] ends 10093960
    unsigned short* wbf  = (unsigned short*)(ws + 10094080); // 108.5KB, in the gap
    unsigned short* h1   = (unsigned short*)(ws + 10485760);          // [N,128]
    unsigned short* xws1 = h1 + (size_t)N_NODES * HID;                // [N,128]
    unsigned short* agg1 = xws1 + (size_t)N_NODES * HID;              // [N,128]
    unsigned short* h2   = xws1;   // EPI3 in-place (read-before-write per thread)
    unsigned short* h3   = h1;     // h1 dead after EPI3
    unsigned short* xws2 = agg1;   // agg1 dead after EPI3
    unsigned short* agg2 = agg1 + (size_t)N_NODES * NCLS;
    unsigned int* pairs  = (unsigned int*)agg1;  // consumed by k_build before cvtx
    unsigned short* xbf  = xws1;   // [N,256] bf16 = xws1+agg1 span; dead after lin1

    // converted-weight segments (elems): lin1_w 32768 | phi1w 16384 | lin2_w 4096 | phi2w 1024
    unsigned short* bw1 = wbf;
    unsigned short* bp1 = wbf + 32768;
    unsigned short* bw2 = wbf + 49152;
    unsigned short* bp2 = wbf + 53248;

    const int GB = 256;
    const int NB5 = (N_NODES + 127) / 128;     // 782 blocks (128 rows/block, 8 waves)
    k_detect<<<1, 256, 0, stream>>>((const unsigned short*)x, dmode);

    // CSR build v3: radix partition, zero global atomics
    k_hist2<<<NCH, 256, 0, stream>>>(ecol, hist, NEDGES);
    k_tot<<<NBK, 256, 0, stream>>>(hist, tot);
    k_bscan<<<1, 1024, 0, stream>>>(tot, bbase);
    k_colscan<<<NBK, 512, 0, stream>>>(hist, bbase, offb);
    k_pass3<<<NCH, 256, 0, stream>>>(erow, ecol, offb, pairs, NEDGES);
    k_build<<<NBK, 256, 0, stream>>>(tot, bbase, pairs, srt, row_start, cend, dinv, N_NODES);

    // antisymmetric weights + bf16 pre-conversion
    k_aw<<<(HID * HID + GB - 1) / GB, GB, 0, stream>>>(W1, aw1, dmode, HID);
    k_aw<<<(NCLS * NCLS + GB - 1) / GB, GB, 0, stream>>>(W2, aw2, dmode, NCLS);
    k_cvtw<<<27, 256, 0, stream>>>(lin1_w, phi1w, lin2_w, phi2w, wbf, dmode);
    k_cvtx<<<2048, 256, 0, stream>>>(x, xbf, dmode, N_NODES * F_IN / 8);

    // h1 = relu(x @ lin1_w.T + lin1_b)   col-split x2 (33.8KB LDS), bf16 path
    k_gemm6<256, 64, 128, 0, 2, true, true><<<NB5 * 2, 512, 0, stream>>>(
        x, xbf, lin1_w, bw1, lin1_b, h1, nullptr, nullptr, nullptr, dmode, nullptr, N_NODES);
    // xws1 = dinv * (h1 @ phi1_w.T)      full B in LDS (34.8KB), one barrier
    k_gemm6<128, 128, 128, 5, 1, false, true><<<NB5, 512, 0, stream>>>(
        h1, nullptr, phi1w, bp1, nullptr, xws1, nullptr, nullptr, dinv, dmode, nullptr, N_NODES);
    // agg1 = dinv * gather(xws1)
    k_gather128<<<(N_NODES + 7) / 8, 256, 0, stream>>>(
        srt, row_start, cend, xws1, dinv, agg1, N_NODES);
    // h2 = h1 + EPS*tanh(h1@aw1.T + agg1 + dinv*xws1 + b1)   (in-place on xws1)
    k_gemm6<128, 128, 128, 3, 1, false, false><<<NB5, 512, 0, stream>>>(
        h1, nullptr, aw1, nullptr, b1, h2, agg1, xws1, dinv, dmode, nullptr, N_NODES);
    // h3 = h2@lin2_w.T + lin2_b ; xws2 = dinv*(h3@phi2_w.T)   (fused)
    k_lin2phi2<<<(N_NODES + 127) / 128, 256, 0, stream>>>(
        h2, lin2_w, bw2, lin2_b, phi2w, bp2, h3, xws2, dinv, dmode, N_NODES);
    // agg2 = dinv * gather(xws2)
    k_gather32<<<(N_NODES + 31) / 32, 256, 0, stream>>>(
        srt, row_start, cend, xws2, dinv, agg2, N_NODES);
    // out = log_softmax(h3 + EPS*tanh(h3@aw2.T + agg2 + dinv*xws2 + b2))  (fused)
    k_gemm6<32, 32, 32, 4, 1, false, false><<<NB5, 512, 0, stream>>>(
        h3, nullptr, aw2, nullptr, b2, nullptr, agg2, xws2, dinv, dmode, d_out, N_NODES);
}